// Round 10
// baseline (739.224 us; speedup 1.0000x reference)
//
#include <hip/hip_runtime.h>
#include <math.h>

typedef unsigned short ushort_t;
typedef __attribute__((ext_vector_type(8))) short short8;
typedef __attribute__((ext_vector_type(4))) float f32x4;
typedef __attribute__((ext_vector_type(4))) _Float16 h16x4;

// ---- dims ----
constexpr int B  = 64;
constexpr int S  = 50;
constexpr int W  = 30;
constexpr int E  = 128;
constexpr int H  = 128;
constexpr int NW = B * S;      // 3200 word sequences
constexpr int V  = 50000;      // vocab
constexpr int NSEQ_G = 8;      // rows per block in sl gin GEMM
constexpr int EP_NB = 256;     // emb_proj blocks per dir (grid-stride, 2/CU)

// ---- intermediates as module-scope device globals ----
// g_P layout is GATE-INTERLEAVED fp16: P[row][j*4 + gate]  (R20)
__device__ _Float16 g_P [(size_t)2 * V * 512];   // 102.4 MB
__device__ float g_wl_h [(size_t)NW * W * 256];  // 98.3 MB
__device__ float g_sent [(size_t)NW * 256];      // 3.28 MB
__device__ float g_gin_f[(size_t)NW * 512];      // 6.55 MB (gate-interleaved)
__device__ float g_gin_b[(size_t)NW * 512];      // 6.55 MB (gate-interleaved)
__device__ float g_sl_h [(size_t)B * S * 256];   // 3.28 MB
__device__ float g_doc  [(size_t)B * 256];       // 64 KB
__device__ ushort_t g_w1hi[128 * 256];           // wa_W1 bf16 hi (presplit)
__device__ ushort_t g_w1lo[128 * 256];           // wa_W1 bf16 lo (presplit)

// ---- helpers ----
__device__ __forceinline__ float sigf(float x) { return 1.0f / (1.0f + __expf(-x)); }
__device__ __forceinline__ float tanh_fast(float x) { return 2.0f / (1.0f + __expf(-2.0f * x)) - 1.0f; }
__device__ __forceinline__ float dot4(float4 a, float4 b) {
    return fmaf(a.x, b.x, fmaf(a.y, b.y, fmaf(a.z, b.z, a.w * b.w)));
}
__device__ __forceinline__ float bf2f(ushort_t u) {
    union { float f; unsigned int i; } v; v.i = ((unsigned int)u) << 16; return v.f;
}
__device__ __forceinline__ ushort_t f2bf(float f) {
    union { float f; unsigned int i; } v; v.f = f;
    unsigned int r = v.i + 0x7fffu + ((v.i >> 16) & 1u);
    return (ushort_t)(r >> 16);
}
// async global->LDS, 16B per lane; lds dest = uniform base + lane*16
__device__ __forceinline__ void gl_lds16(const void* g, void* lds_base) {
    __builtin_amdgcn_global_load_lds(
        (const __attribute__((address_space(1))) unsigned int*)g,
        (__attribute__((address_space(3))) unsigned int*)lds_base, 16, 0, 0);
}

// ============================================================
// K-1: presplit wa_W1 into bf16 hi/lo global arrays. Unchanged R19.
// ============================================================
__global__ __launch_bounds__(256) void k_split_w1(const float* __restrict__ W1)
{
    const int i = (blockIdx.x * 256 + threadIdx.x) * 4;
    if (i >= 128 * 256) return;
    float4 v = *(const float4*)&W1[i];
    ushort_t h0 = f2bf(v.x), h1 = f2bf(v.y), h2 = f2bf(v.z), h3 = f2bf(v.w);
    *(ushort4*)&g_w1hi[i] = make_ushort4(h0, h1, h2, h3);
    *(ushort4*)&g_w1lo[i] = make_ushort4(
        f2bf(v.x - bf2f(h0)), f2bf(v.y - bf2f(h1)),
        f2bf(v.z - bf2f(h2)), f2bf(v.w - bf2f(h3)));
}

// ============================================================
// K0: vocab input projection via MFMA (split-bf16 3-pass).
// R20: P stored fp16. Unchanged from R9 (736us config).
// ============================================================
__global__ __launch_bounds__(512, 2) void k_emb_proj(
    const float* __restrict__ emb,
    const float* __restrict__ Wih_f, const float* __restrict__ bih_f, const float* __restrict__ bhh_f,
    const float* __restrict__ Wih_b, const float* __restrict__ bih_b, const float* __restrict__ bhh_b)
{
    constexpr int NT = V / 16;   // 3125
    const int dir = blockIdx.x & 1;
    const int bid = blockIdx.x >> 1;      // 0..EP_NB-1
    const float* Wih = dir ? Wih_b : Wih_f;
    const float* bih = dir ? bih_b : bih_f;
    const float* bhh = dir ? bhh_b : bhh_f;
    _Float16* P = g_P + (size_t)dir * V * 512;

    const int tid  = threadIdx.x;
    const int wv   = tid >> 6;
    const int lane = tid & 63;
    const int l15  = lane & 15;
    const int q    = lane >> 4;

    short8 bhi[4][4], blo[4][4];
    #pragma unroll
    for (int nt = 0; nt < 4; ++nt) {
        const float* wrow = Wih + (size_t)(wv * 64 + nt * 16 + l15) * E;
        #pragma unroll
        for (int kt = 0; kt < 4; ++kt) {
            const float* wp = wrow + kt * 32 + q * 8;
            short8 h8, l8;
            #pragma unroll
            for (int i = 0; i < 8; ++i) {
                float f = wp[i];
                ushort_t hb = f2bf(f);
                h8[i] = (short)hb;
                l8[i] = (short)f2bf(f - bf2f(hb));
            }
            bhi[nt][kt] = h8;
            blo[nt][kt] = l8;
        }
    }

    const int cb = (tid * 4) & 511;
    const int jj = cb >> 2;
    float4 bias4 = make_float4(bih[jj]       + bhh[jj],
                               bih[128 + jj] + bhh[128 + jj],
                               bih[256 + jj] + bhh[256 + jj],
                               bih[384 + jj] + bhh[384 + jj]);

    __shared__ __align__(16) float xs[2][2048];   // raw emb tile, dbuf (16KB)
    __shared__ ushort_t xh[16][136];              // bf16 hi (4.3KB)
    __shared__ ushort_t xl[16][136];              // bf16 lo (4.3KB)
    __shared__ float    os[16][516];              // out staging (33KB)

    int tile = bid;
    if (tile < NT)
        gl_lds16(emb + (size_t)tile * 2048 + wv * 256 + lane * 4, &xs[0][wv * 256]);
    int cur = 0;
    bool first = true;

    for (; tile < NT; tile += EP_NB) {
        if (first) { asm volatile("s_waitcnt vmcnt(0)" ::: "memory"); }
        else       { asm volatile("s_waitcnt vmcnt(4)" ::: "memory"); }
        asm volatile("s_waitcnt lgkmcnt(0)" ::: "memory");
        __builtin_amdgcn_sched_barrier(0);
        __builtin_amdgcn_s_barrier();
        first = false;

        if (tile + EP_NB < NT)
            gl_lds16(emb + (size_t)(tile + EP_NB) * 2048 + wv * 256 + lane * 4,
                     &xs[cur ^ 1][wv * 256]);

        {
            const int idx = tid * 4;
            const int row = idx >> 7, col = idx & 127;
            float4 v = *(const float4*)&xs[cur][idx];
            ushort_t h0 = f2bf(v.x), h1 = f2bf(v.y), h2 = f2bf(v.z), h3 = f2bf(v.w);
            *(ushort4*)&xh[row][col] = make_ushort4(h0, h1, h2, h3);
            *(ushort4*)&xl[row][col] = make_ushort4(
                f2bf(v.x - bf2f(h0)), f2bf(v.y - bf2f(h1)),
                f2bf(v.z - bf2f(h2)), f2bf(v.w - bf2f(h3)));
        }
        asm volatile("s_waitcnt lgkmcnt(0)" ::: "memory");
        __builtin_amdgcn_sched_barrier(0);
        __builtin_amdgcn_s_barrier();

        short8 ahi[4], alo[4];
        #pragma unroll
        for (int kt = 0; kt < 4; ++kt) {
            ahi[kt] = *(const short8*)&xh[l15][kt * 32 + q * 8];
            alo[kt] = *(const short8*)&xl[l15][kt * 32 + q * 8];
        }

        f32x4 acc[4];
        #pragma unroll
        for (int nt = 0; nt < 4; ++nt) acc[nt] = (f32x4){0.f, 0.f, 0.f, 0.f};
        #pragma unroll
        for (int kt = 0; kt < 4; ++kt) {
            #pragma unroll
            for (int nt = 0; nt < 4; ++nt) {
                acc[nt] = __builtin_amdgcn_mfma_f32_16x16x32_bf16(ahi[kt], bhi[nt][kt], acc[nt], 0, 0, 0);
                acc[nt] = __builtin_amdgcn_mfma_f32_16x16x32_bf16(alo[kt], bhi[nt][kt], acc[nt], 0, 0, 0);
                acc[nt] = __builtin_amdgcn_mfma_f32_16x16x32_bf16(ahi[kt], blo[nt][kt], acc[nt], 0, 0, 0);
            }
        }

        #pragma unroll
        for (int nt = 0; nt < 4; ++nt) {
            const int c0 = wv * 64 + nt * 16;
            #pragma unroll
            for (int r = 0; r < 4; ++r) {
                const int c = c0 + l15;
                os[q * 4 + r][((c & 127) << 2) | (c >> 7)] = acc[nt][r];
            }
        }
        asm volatile("s_waitcnt lgkmcnt(0)" ::: "memory");
        __builtin_amdgcn_sched_barrier(0);
        __builtin_amdgcn_s_barrier();

        // stream staging -> P (fp16, 8B per 4 gates; 4 stores/thread)
        const int r0 = tile * 16;
        #pragma unroll
        for (int i = tid * 4; i < 16 * 512; i += 2048) {
            const int row = i >> 9, col = i & 511;
            float4 v = *(const float4*)&os[row][col];
            h16x4 hv;
            hv.x = (_Float16)(v.x + bias4.x);
            hv.y = (_Float16)(v.y + bias4.y);
            hv.z = (_Float16)(v.z + bias4.z);
            hv.w = (_Float16)(v.w + bias4.w);
            *(h16x4*)&P[(size_t)(r0 + row) * 512 + col] = hv;
        }
        cur ^= 1;
    }
}

// ============================================================
// K1: word BiLSTM recurrence via MFMA, split-bf16.
// R21: DOUBLE-BUFFERED pg slab + prefetch issued at step TOP
// (before MFMA) -> each gather gets a FULL step (~13k cyc) of
// flight, covering the ~900cy HBM miss latency (FETCH shows the
// P-gathers miss L3). Counted waits:
//   st=0:   queue [L0, L1]               -> vmcnt(8)
//   middle: queue [L_st, S_{st-1}, L_{st+1}] -> vmcnt(16)
//   st=W-1: queue [L_{W-1}, S_{W-2}]     -> vmcnt(8)
// Overwrite safety: buf[pb^1] was read at st-1, whose trailing
// lgkmcnt(0)+barrier precedes this step's prefetch issue.
// ============================================================
__global__ __launch_bounds__(512, 2) void k_word_lstm(
    const int* __restrict__ ids,
    const float* __restrict__ Whh_f, const float* __restrict__ Whh_b)
{
    const int dir = blockIdx.x & 1;
    const int s0  = (blockIdx.x >> 1) * 32;          // 32 seqs per block
    const float* Whh = dir ? Whh_b : Whh_f;
    const _Float16* Pp = g_P + (size_t)dir * V * 512;

    __shared__ ushort_t sh_hhi[2][2][16][136];       // [buf][unit][row][col]
    __shared__ ushort_t sh_hlo[2][2][16][136];
    __shared__ int      ids_sh[32 * W];
    __shared__ __align__(16) _Float16 pgbuf[2][8][2][16][64]; // [buf][wave][u][seq][64] 64KB

    const int tid  = threadIdx.x;
    const int wv   = tid >> 6;
    const int lane = tid & 63;
    const int l15  = lane & 15;
    const int q    = lane >> 4;
    const int jc   = wv * 16 + l15;                  // owned hidden col
    const int l7   = lane & 7;                       // col-pair within gather
    const int sq8  = lane >> 3;                      // seq within gather call

    // persistent B-frags: output col c = nt*128 + jc  ->  Whh row c
    short8 bhi[4][4], blo[4][4];
    #pragma unroll
    for (int nt = 0; nt < 4; ++nt) {
        const float* wrow = Whh + (size_t)(nt * 128 + jc) * H;
        #pragma unroll
        for (int kt = 0; kt < 4; ++kt) {
            const float* wp = wrow + kt * 32 + q * 8;
            short8 h8, l8;
            #pragma unroll
            for (int i = 0; i < 8; ++i) {
                float f = wp[i];
                ushort_t hb = f2bf(f);
                h8[i] = (short)hb;
                l8[i] = (short)f2bf(f - bf2f(hb));
            }
            bhi[nt][kt] = h8;
            blo[nt][kt] = l8;
        }
    }

    for (int i = tid; i < 32 * W; i += 512) ids_sh[i] = ids[s0 * W + i];
    for (int i = tid; i < 2 * 2 * 16 * 136; i += 512) {
        (&sh_hhi[0][0][0][0])[i] = 0;
        (&sh_hlo[0][0][0][0])[i] = 0;
    }
    float cst[2][4];
    #pragma unroll
    for (int u = 0; u < 2; ++u)
        #pragma unroll
        for (int r = 0; r < 4; ++r) cst[u][r] = 0.f;
    __syncthreads();

    // prologue: issue gathers for step 0 into pgbuf[0]
    {
        const int t0 = dir ? (W - 1) : 0;
        #pragma unroll
        for (int u = 0; u < 2; ++u)
            #pragma unroll
            for (int c = 0; c < 2; ++c) {
                const int sq = c * 8 + sq8;
                const _Float16* gsrc = Pp + (size_t)ids_sh[(u * 16 + sq) * W + t0] * 512
                                          + (wv * 16 + l7 * 2) * 4;
                gl_lds16(gsrc, &pgbuf[0][wv][u][c * 8][0]);
            }
    }

    for (int st = 0; st < W; ++st) {
        const int t  = dir ? (W - 1 - st) : st;
        const int p  = st & 1;
        const int pb = st & 1;                       // pg buffer for this step

        // ---- issue prefetch for step st+1 FIRST (full-step flight) ----
        if (st + 1 < W) {
            const int tn = dir ? (W - 2 - st) : st + 1;
            #pragma unroll
            for (int u = 0; u < 2; ++u)
                #pragma unroll
                for (int c = 0; c < 2; ++c) {
                    const int sq = c * 8 + sq8;
                    const _Float16* gsrc = Pp + (size_t)ids_sh[(u * 16 + sq) * W + tn] * 512
                                              + (wv * 16 + l7 * 2) * 4;
                    gl_lds16(gsrc, &pgbuf[pb ^ 1][wv][u][c * 8][0]);
                }
        }
        __builtin_amdgcn_sched_barrier(0);

        // ---- MFMA on h(t-1) from LDS buf p (zero-init acc, no mem dep) ----
        f32x4 acc[2][4];
        #pragma unroll
        for (int u = 0; u < 2; ++u)
            #pragma unroll
            for (int nt = 0; nt < 4; ++nt) acc[u][nt] = (f32x4){0.f, 0.f, 0.f, 0.f};

        #pragma unroll
        for (int u = 0; u < 2; ++u) {
            const ushort_t* ph = &sh_hhi[p][u][l15][q * 8];
            const ushort_t* pl = &sh_hlo[p][u][l15][q * 8];
            #pragma unroll
            for (int kt = 0; kt < 4; ++kt) {
                short8 ahi = *(const short8*)(ph + kt * 32);
                short8 alo = *(const short8*)(pl + kt * 32);
                #pragma unroll
                for (int nt = 0; nt < 4; ++nt) {
                    acc[u][nt] = __builtin_amdgcn_mfma_f32_16x16x32_bf16(ahi, bhi[nt][kt], acc[u][nt], 0, 0, 0);
                    acc[u][nt] = __builtin_amdgcn_mfma_f32_16x16x32_bf16(alo, bhi[nt][kt], acc[u][nt], 0, 0, 0);
                    acc[u][nt] = __builtin_amdgcn_mfma_f32_16x16x32_bf16(ahi, blo[nt][kt], acc[u][nt], 0, 0, 0);
                }
            }
        }

        // ---- counted wait: retire exactly this step's 8 loads ----
        if (st == 0 || st == W - 1) { asm volatile("s_waitcnt vmcnt(8)"  ::: "memory"); }
        else                        { asm volatile("s_waitcnt vmcnt(16)" ::: "memory"); }
        __builtin_amdgcn_sched_barrier(0);

        // pg readback: 4 fp16 gates per (u,r) at pgbuf[pb][wv][u][s][l15*4]
        float4 pg[2][4];
        #pragma unroll
        for (int u = 0; u < 2; ++u)
            #pragma unroll
            for (int r = 0; r < 4; ++r) {
                const int s = q * 4 + r;
                h16x4 hv = *(const h16x4*)&pgbuf[pb][wv][u][s][l15 * 4];
                pg[u][r] = make_float4((float)hv.x, (float)hv.y, (float)hv.z, (float)hv.w);
            }
        asm volatile("s_waitcnt lgkmcnt(0)" ::: "memory");
        __builtin_amdgcn_sched_barrier(0);

        // ---- gates fully in-register ----
        #pragma unroll
        for (int u = 0; u < 2; ++u) {
            #pragma unroll
            for (int r = 0; r < 4; ++r) {
                const int s = q * 4 + r;
                float gi = acc[u][0][r] + pg[u][r].x;
                float gf = acc[u][1][r] + pg[u][r].y;
                float gg = acc[u][2][r] + pg[u][r].z;
                float go = acc[u][3][r] + pg[u][r].w;
                float c = sigf(gf) * cst[u][r] + sigf(gi) * tanh_fast(gg);
                float h = sigf(go) * tanh_fast(c);
                cst[u][r] = c;
                g_wl_h[((size_t)(s0 + u * 16 + s) * W + t) * 256 + dir * H + jc] = h;
                ushort_t hb = f2bf(h);
                sh_hhi[p ^ 1][u][s][jc] = hb;
                sh_hlo[p ^ 1][u][s][jc] = f2bf(h - bf2f(hb));
            }
        }

        // raw barrier: drain LDS ops only, keep prefetch loads in flight
        asm volatile("s_waitcnt lgkmcnt(0)" ::: "memory");
        __builtin_amdgcn_sched_barrier(0);
        __builtin_amdgcn_s_barrier();
    }
}

// ============================================================
// K2: FUSED word attention (scores + softmax + pool). Unchanged R19.
// ============================================================
__global__ __launch_bounds__(256, 2) void k_word_attn(
    const int* __restrict__ ids,
    const float* __restrict__ b1, const float* __restrict__ W2,
    const float* __restrict__ b2)
{
    const int n    = blockIdx.x;
    const int tid  = threadIdx.x;
    const int wv   = tid >> 6;        // 0..3
    const int lane = tid & 63;
    const int l15  = lane & 15;
    const int q    = lane >> 4;

    __shared__ float    hsh[W][256];  // 30 KB
    __shared__ ushort_t xhi[32][264]; // 16.9 KB
    __shared__ ushort_t xlo[32][264];
    __shared__ float    part[4][32];
    __shared__ float    wsh[32];

    short8 bhi[2][8], blo[2][8];
    float  b1n[2], w2n[2];
    #pragma unroll
    for (int ntl = 0; ntl < 2; ++ntl) {
        const int c = (2 * wv + ntl) * 16 + l15;
        #pragma unroll
        for (int kt = 0; kt < 8; ++kt) {
            bhi[ntl][kt] = *(const short8*)&g_w1hi[c * 256 + kt * 32 + q * 8];
            blo[ntl][kt] = *(const short8*)&g_w1lo[c * 256 + kt * 32 + q * 8];
        }
        b1n[ntl] = b1[c];
        w2n[ntl] = W2[c];
    }
    const float b2v = b2[0];

    const float* src = g_wl_h + (size_t)n * W * 256;
    for (int i = tid * 4; i < W * 256; i += 1024) {
        const int row = i >> 8, col = i & 255;
        float4 v = *(const float4*)&src[i];
        *(float4*)&hsh[row][col] = v;
        ushort_t h0 = f2bf(v.x), h1 = f2bf(v.y), h2 = f2bf(v.z), h3 = f2bf(v.w);
        *(ushort4*)&xhi[row][col] = make_ushort4(h0, h1, h2, h3);
        *(ushort4*)&xlo[row][col] = make_ushort4(
            f2bf(v.x - bf2f(h0)), f2bf(v.y - bf2f(h1)),
            f2bf(v.z - bf2f(h2)), f2bf(v.w - bf2f(h3)));
    }
    for (int i = tid; i < 2 * 264; i += 256) {
        (&xhi[30][0])[i] = 0;
        (&xlo[30][0])[i] = 0;
    }
    __syncthreads();

    float vr[2][4];
    #pragma unroll
    for (int rt = 0; rt < 2; ++rt) {
        short8 ahi[8], alo[8];
        #pragma unroll
        for (int kt = 0; kt < 8; ++kt) {
            ahi[kt] = *(const short8*)&xhi[rt * 16 + l15][kt * 32 + q * 8];
            alo[kt] = *(const short8*)&xlo[rt * 16 + l15][kt * 32 + q * 8];
        }
        #pragma unroll
        for (int ntl = 0; ntl < 2; ++ntl) {
            f32x4 acc = (f32x4){0.f, 0.f, 0.f, 0.f};
            #pragma unroll
            for (int kt = 0; kt < 8; ++kt) {
                acc = __builtin_amdgcn_mfma_f32_16x16x32_bf16(ahi[kt], bhi[ntl][kt], acc, 0, 0, 0);
                acc = __builtin_amdgcn_mfma_f32_16x16x32_bf16(alo[kt], bhi[ntl][kt], acc, 0, 0, 0);
                acc = __builtin_amdgcn_mfma_f32_16x16x32_bf16(ahi[kt], blo[ntl][kt], acc, 0, 0, 0);
            }
            #pragma unroll
            for (int r = 0; r < 4; ++r) {
                float u = tanh_fast(acc[r] + b1n[ntl]) * w2n[ntl];
                if (ntl == 0) vr[rt][r] = u; else vr[rt][r] += u;
            }
        }
    }
    #pragma unroll
    for (int rt = 0; rt < 2; ++rt)
        #pragma unroll
        for (int r = 0; r < 4; ++r) {
            float v = vr[rt][r];
            v += __shfl_xor(v, 1, 64);
            v += __shfl_xor(v, 2, 64);
            v += __shfl_xor(v, 4, 64);
            v += __shfl_xor(v, 8, 64);
            vr[rt][r] = v;
        }
    if (l15 == 0) {
        #pragma unroll
        for (int rt = 0; rt < 2; ++rt)
            #pragma unroll
            for (int r = 0; r < 4; ++r)
                part[wv][rt * 16 + q * 4 + r] = vr[rt][r];
    }
    __syncthreads();

    if (tid < 32) {
        const int t = tid;
        float s = b2v + part[0][t] + part[1][t] + part[2][t] + part[3][t];
        bool valid = (t < W) && (ids[n * W + t] != 0);
        wsh[t] = valid ? s : -INFINITY;
    }
    __syncthreads();

    if (tid < 64) {
        float v = (tid < W) ? wsh[tid] : -INFINITY;
        float m = v;
        #pragma unroll
        for (int off = 32; off > 0; off >>= 1) m = fmaxf(m, __shfl_xor(m, off, 64));
        float e = (v == -INFINITY) ? 0.f : __expf(v - m);
        float ssum = e;
        #pragma unroll
        for (int off = 32; off > 0; off >>= 1) ssum += __shfl_xor(ssum, off, 64);
        const float inv = (ssum > 0.f) ? 1.f / ssum : 0.f;
        if (tid < W) wsh[tid] = e * inv;
    }
    __syncthreads();

    float o = 0.f;
    #pragma unroll
    for (int t = 0; t < W; ++t) o += wsh[t] * hsh[t][tid];
    g_sent[(size_t)n * 256 + tid] = o;
}

// ============================================================
// K3: sentence LSTM input projection. Store gate-interleaved. Unchanged.
// ============================================================
__global__ __launch_bounds__(256) void k_sl_gin(
    const float* __restrict__ Wih_f, const float* __restrict__ bih_f, const float* __restrict__ bhh_f,
    const float* __restrict__ Wih_b, const float* __restrict__ bih_b, const float* __restrict__ bhh_b)
{
    const int dir = blockIdx.x & 1;
    const float* Wih = dir ? Wih_b : Wih_f;
    const float* bih = dir ? bih_b : bih_f;
    const float* bhh = dir ? bhh_b : bhh_f;
    float* gin = dir ? g_gin_b : g_gin_f;
    const int r0 = (blockIdx.x >> 1) * NSEQ_G;

    __shared__ float xs[NSEQ_G][256];
    const int tid = threadIdx.x;
    for (int i = tid * 4; i < NSEQ_G * 256; i += 1024)
        *(float4*)&(&xs[0][0])[i] = *(const float4*)&g_sent[(size_t)r0 * 256 + i];
    __syncthreads();

    const int g0 = tid, g1 = tid + 256;
    float acc0[NSEQ_G], acc1[NSEQ_G];
    #pragma unroll
    for (int s = 0; s < NSEQ_G; ++s) { acc0[s] = 0.f; acc1[s] = 0.f; }
    const float* w0 = &Wih[g0 * 256]; const float* w1 = &Wih[g1 * 256];
    for (int k = 0; k < 256; k += 4) {
        float4 wa = *(const float4*)(w0 + k);
        float4 wb = *(const float4*)(w1 + k);
        #pragma unroll
        for (int s = 0; s < NSEQ_G; ++s) {
            float4 xv = *(const float4*)&xs[s][k];
            acc0[s] += dot4(wa, xv);
            acc1[s] += dot4(wb, xv);
        }
    }
    const float bv0 = bih[g0] + bhh[g0];
    const float bv1 = bih[g1] + bhh[g1];
    const int p0 = ((g0 & 127) << 2) | (g0 >> 7);
    const int p1 = ((g1 & 127) << 2) | (g1 >> 7);
    #pragma unroll
    for (int s = 0; s < NSEQ_G; ++s) {
        gin[(size_t)(r0 + s) * 512 + p0] = acc0[s] + bv0;
        gin[(size_t)(r0 + s) * 512 + p1] = acc1[s] + bv1;
    }
}

// ============================================================
// K4: sentence BiLSTM via MFMA col-block recurrence. Unchanged R18.
// ============================================================
__global__ __launch_bounds__(512, 2) void k_sent_lstm(
    const float* __restrict__ Whh_f, const float* __restrict__ Whh_b)
{
    const int dir = blockIdx.x & 1;
    const int s0  = (blockIdx.x >> 1) * 16;          // 16 docs per block
    const float* Whh = dir ? Whh_b : Whh_f;
    const float* gin = dir ? g_gin_b : g_gin_f;

    __shared__ ushort_t sh_hhi[2][16][136];
    __shared__ ushort_t sh_hlo[2][16][136];

    const int tid  = threadIdx.x;
    const int wv   = tid >> 6;
    const int lane = tid & 63;
    const int l15  = lane & 15;
    const int q    = lane >> 4;
    const int jc   = wv * 16 + l15;

    short8 bhi[4][4], blo[4][4];
    #pragma unroll
    for (int nt = 0; nt < 4; ++nt) {
        const float* wrow = Whh + (size_t)(nt * 128 + jc) * H;
        #pragma unroll
        for (int kt = 0; kt < 4; ++kt) {
            const float* wp = wrow + kt * 32 + q * 8;
            short8 h8, l8;
            #pragma unroll
            for (int i = 0; i < 8; ++i) {
                float f = wp[i];
                ushort_t hb = f2bf(f);
                h8[i] = (short)hb;
                l8[i] = (short)f2bf(f - bf2f(hb));
            }
            bhi[nt][kt] = h8;
            blo[nt][kt] = l8;
        }
    }

    for (int i = tid; i < 2 * 16 * 136; i += 512) {
        (&sh_hhi[0][0][0])[i] = 0;
        (&sh_hlo[0][0][0])[i] = 0;
    }
    float cst[4] = {0.f, 0.f, 0.f, 0.f};
    __syncthreads();

    for (int st = 0; st < S; ++st) {
        const int t = dir ? (S - 1 - st) : st;
        const int p = st & 1;

        float4 pg[4];
        #pragma unroll
        for (int r = 0; r < 4; ++r) {
            const int b = s0 + q * 4 + r;
            pg[r] = *(const float4*)(gin + (size_t)(b * S + t) * 512 + jc * 4);
        }

        f32x4 acc[4];
        #pragma unroll
        for (int nt = 0; nt < 4; ++nt) acc[nt] = (f32x4){0.f, 0.f, 0.f, 0.f};
        {
            const ushort_t* ph = &sh_hhi[p][l15][q * 8];
            const ushort_t* pl = &sh_hlo[p][l15][q * 8];
            #pragma unroll
            for (int kt = 0; kt < 4; ++kt) {
                short8 ahi = *(const short8*)(ph + kt * 32);
                short8 alo = *(const short8*)(pl + kt * 32);
                #pragma unroll
                for (int nt = 0; nt < 4; ++nt) {
                    acc[nt] = __builtin_amdgcn_mfma_f32_16x16x32_bf16(ahi, bhi[nt][kt], acc[nt], 0, 0, 0);
                    acc[nt] = __builtin_amdgcn_mfma_f32_16x16x32_bf16(alo, bhi[nt][kt], acc[nt], 0, 0, 0);
                    acc[nt] = __builtin_amdgcn_mfma_f32_16x16x32_bf16(ahi, blo[nt][kt], acc[nt], 0, 0, 0);
                }
            }
        }

        #pragma unroll
        for (int r = 0; r < 4; ++r) {
            const int s = q * 4 + r;
            const int b = s0 + s;
            float gi = acc[0][r] + pg[r].x;
            float gf = acc[1][r] + pg[r].y;
            float gg = acc[2][r] + pg[r].z;
            float go = acc[3][r] + pg[r].w;
            float c = sigf(gf) * cst[r] + sigf(gi) * tanh_fast(gg);
            float h = sigf(go) * tanh_fast(c);
            cst[r] = c;
            g_sl_h[(size_t)(b * S + t) * 256 + dir * H + jc] = h;
            ushort_t hb = f2bf(h);
            sh_hhi[p ^ 1][s][jc] = hb;
            sh_hlo[p ^ 1][s][jc] = f2bf(h - bf2f(hb));
        }
        __syncthreads();
    }
}

// ============================================================
// K5: document attention pool. Wave-parallel softmax. Unchanged.
// ============================================================
template <int T>
__global__ __launch_bounds__(128) void k_attn_pool_doc(
    const int* __restrict__ ids,
    const float* __restrict__ W1, const float* __restrict__ b1,
    const float* __restrict__ W2, const float* __restrict__ b2)
{
    constexpr int TH = T / 2;
    const int n = blockIdx.x;
    __shared__ float hsh[T][256];
    __shared__ float wsh[T];
    const int tid = threadIdx.x;
    const int lane = tid & 63;
    const int wv   = tid >> 6;

    const float* src = g_sl_h + (size_t)n * T * 256;
    for (int i = tid * 4; i < T * 256; i += 512)
        *(float4*)&(&hsh[0][0])[i] = *(const float4*)&src[i];
    __syncthreads();

    const int j0 = lane, j1 = lane + 64;
    const int tbase = wv * TH;
    float acc0[TH], acc1[TH];
    #pragma unroll
    for (int u = 0; u < TH; ++u) { acc0[u] = 0.f; acc1[u] = 0.f; }
    const float* w1a = &W1[j0 * 256];
    const float* w1b = &W1[j1 * 256];
    for (int k = 0; k < 256; k += 4) {
        float4 wa = *(const float4*)(w1a + k);
        float4 wb = *(const float4*)(w1b + k);
        #pragma unroll
        for (int u = 0; u < TH; ++u) {
            float4 hv = *(const float4*)&hsh[tbase + u][k];
            acc0[u] += dot4(wa, hv);
            acc1[u] += dot4(wb, hv);
        }
    }
    const float b1a = b1[j0], b1b = b1[j1];
    const float w2a = W2[j0], w2b = W2[j1];
    #pragma unroll
    for (int u = 0; u < TH; ++u) {
        float v = w2a * tanh_fast(acc0[u] + b1a) + w2b * tanh_fast(acc1[u] + b1b);
        #pragma unroll
        for (int off = 32; off > 0; off >>= 1) v += __shfl_down(v, off, 64);
        if (lane == 0) wsh[tbase + u] = v;
    }
    __syncthreads();

    if (tid < T) {
        bool valid = false;
        const int* ip = &ids[((size_t)n * T + tid) * W];
        for (int w = 0; w < W; ++w) valid |= (ip[w] != 0);
        wsh[tid] = valid ? (wsh[tid] + b2[0]) : -INFINITY;
    }
    __syncthreads();
    if (tid < 64) {
        float v = (tid < T) ? wsh[tid] : -INFINITY;
        float m = v;
        #pragma unroll
        for (int off = 32; off > 0; off >>= 1) m = fmaxf(m, __shfl_xor(m, off, 64));
        float e = (v == -INFINITY) ? 0.f : __expf(v - m);
        float ssum = e;
        #pragma unroll
        for (int off = 32; off > 0; off >>= 1) ssum += __shfl_xor(ssum, off, 64);
        const float inv = (ssum > 0.f) ? 1.f / ssum : 0.f;
        if (tid < T) wsh[tid] = e * inv;
    }
    __syncthreads();

    float o0 = 0.f, o1 = 0.f;
    #pragma unroll
    for (int t = 0; t < T; ++t) {
        float w = wsh[t];
        o0 += w * hsh[t][tid];
        o1 += w * hsh[t][tid + 128];
    }
    g_doc[(size_t)n * 256 + tid] = o0;
    g_doc[(size_t)n * 256 + tid + 128] = o1;
}

// ============================================================
// K6: classifier. Unchanged.
// ============================================================
__global__ __launch_bounds__(128) void k_classifier(
    const float* __restrict__ W1, const float* __restrict__ b1,
    const float* __restrict__ W2, const float* __restrict__ b2,
    float* __restrict__ out)
{
    const int b = blockIdx.x;
    __shared__ float dsh[256];
    __shared__ float hsh[128];
    const int tid = threadIdx.x;
    if (tid < 64) *(float4*)&dsh[tid * 4] = *(const float4*)&g_doc[(size_t)b * 256 + tid * 4];
    __syncthreads();
    float acc = 0.f;
    const float* w1p = &W1[tid * 256];
    for (int k = 0; k < 256; k += 4) {
        float4 w4 = *(const float4*)(w1p + k);
        float4 d4 = *(const float4*)&dsh[k];
        acc += dot4(w4, d4);
    }
    hsh[tid] = fmaxf(acc + b1[tid], 0.f);
    __syncthreads();
    if (tid < 3) {
        float a = b2[tid];
        const float* w2p = &W2[tid * 128];
        for (int j = 0; j < 128; ++j) a += w2p[j] * hsh[j];
        out[b * 3 + tid] = a;
    }
}

// ============================================================
extern "C" void kernel_launch(void* const* d_in, const int* in_sizes, int n_in,
                              void* d_out, int out_size, void* d_ws, size_t ws_size,
                              hipStream_t stream) {
    const int*   ids      = (const int*)d_in[0];
    const float* emb      = (const float*)d_in[1];
    const float* wl_Wih_f = (const float*)d_in[2];
    const float* wl_Whh_f = (const float*)d_in[3];
    const float* wl_bih_f = (const float*)d_in[4];
    const float* wl_bhh_f = (const float*)d_in[5];
    const float* wl_Wih_b = (const float*)d_in[6];
    const float* wl_Whh_b = (const float*)d_in[7];
    const float* wl_bih_b = (const float*)d_in[8];
    const float* wl_bhh_b = (const float*)d_in[9];
    const float* sl_Wih_f = (const float*)d_in[10];
    const float* sl_Whh_f = (const float*)d_in[11];
    const float* sl_bih_f = (const float*)d_in[12];
    const float* sl_bhh_f = (const float*)d_in[13];
    const float* sl_Wih_b = (const float*)d_in[14];
    const float* sl_Whh_b = (const float*)d_in[15];
    const float* sl_bih_b = (const float*)d_in[16];
    const float* sl_bhh_b = (const float*)d_in[17];
    const float* wa_W1 = (const float*)d_in[18];
    const float* wa_b1 = (const float*)d_in[19];
    const float* wa_W2 = (const float*)d_in[20];
    const float* wa_b2 = (const float*)d_in[21];
    const float* sa_W1 = (const float*)d_in[22];
    const float* sa_b1 = (const float*)d_in[23];
    const float* sa_W2 = (const float*)d_in[24];
    const float* sa_b2 = (const float*)d_in[25];
    const float* cl_W1 = (const float*)d_in[26];
    const float* cl_b1 = (const float*)d_in[27];
    const float* cl_W2 = (const float*)d_in[28];
    const float* cl_b2 = (const float*)d_in[29];

    k_split_w1<<<32, 256, 0, stream>>>(wa_W1);

    k_emb_proj<<<EP_NB * 2, 512, 0, stream>>>(
        emb, wl_Wih_f, wl_bih_f, wl_bhh_f, wl_Wih_b, wl_bih_b, wl_bhh_b);

    k_word_lstm<<<(NW / 32) * 2, 512, 0, stream>>>(ids, wl_Whh_f, wl_Whh_b);

    k_word_attn<<<NW, 256, 0, stream>>>(ids, wa_b1, wa_W2, wa_b2);

    k_sl_gin<<<NW / NSEQ_G * 2, 256, 0, stream>>>(
        sl_Wih_f, sl_bih_f, sl_bhh_f, sl_Wih_b, sl_bih_b, sl_bhh_b);

    k_sent_lstm<<<(B / 16) * 2, 512, 0, stream>>>(sl_Whh_f, sl_Whh_b);

    k_attn_pool_doc<S><<<B, 128, 0, stream>>>(ids, sa_W1, sa_b1, sa_W2, sa_b2);

    k_classifier<<<B, 128, 0, stream>>>(cl_W1, cl_b1, cl_W2, cl_b2, (float*)d_out);
}

// Round 11
// 733.114 us; speedup vs baseline: 1.0083x; 1.0083x over previous
//
#include <hip/hip_runtime.h>
#include <math.h>

typedef unsigned short ushort_t;
typedef __attribute__((ext_vector_type(8))) short short8;
typedef __attribute__((ext_vector_type(4))) float f32x4;
typedef __attribute__((ext_vector_type(4))) _Float16 h16x4;

// ---- dims ----
constexpr int B  = 64;
constexpr int S  = 50;
constexpr int W  = 30;
constexpr int E  = 128;
constexpr int H  = 128;
constexpr int NW = B * S;      // 3200 word sequences
constexpr int V  = 50000;      // vocab
constexpr int NSEQ_G = 8;      // rows per block in sl gin GEMM
constexpr int EP_NB = 256;     // emb_proj blocks per dir (grid-stride, 2/CU)

// ---- intermediates as module-scope device globals ----
// g_P GATE-INTERLEAVED fp16 (R20); g_wl_h fp16 (R22).
__device__ _Float16 g_P  [(size_t)2 * V * 512];   // 102.4 MB
__device__ _Float16 g_wl_h[(size_t)NW * W * 256]; // 49.2 MB
__device__ float g_sent [(size_t)NW * 256];       // 3.28 MB
__device__ float g_gin_f[(size_t)NW * 512];       // 6.55 MB (gate-interleaved)
__device__ float g_gin_b[(size_t)NW * 512];       // 6.55 MB (gate-interleaved)
__device__ float g_sl_h [(size_t)B * S * 256];    // 3.28 MB
__device__ float g_doc  [(size_t)B * 256];        // 64 KB
__device__ ushort_t g_w1hi[128 * 256];            // wa_W1 bf16 hi (presplit)
__device__ ushort_t g_w1lo[128 * 256];            // wa_W1 bf16 lo (presplit)

// ---- helpers ----
__device__ __forceinline__ float sigf(float x) { return 1.0f / (1.0f + __expf(-x)); }
__device__ __forceinline__ float tanh_fast(float x) { return 2.0f / (1.0f + __expf(-2.0f * x)) - 1.0f; }
__device__ __forceinline__ float dot4(float4 a, float4 b) {
    return fmaf(a.x, b.x, fmaf(a.y, b.y, fmaf(a.z, b.z, a.w * b.w)));
}
__device__ __forceinline__ float bf2f(ushort_t u) {
    union { float f; unsigned int i; } v; v.i = ((unsigned int)u) << 16; return v.f;
}
__device__ __forceinline__ ushort_t f2bf(float f) {
    union { float f; unsigned int i; } v; v.f = f;
    unsigned int r = v.i + 0x7fffu + ((v.i >> 16) & 1u);
    return (ushort_t)(r >> 16);
}
// async global->LDS, 16B per lane; lds dest = uniform base + lane*16
__device__ __forceinline__ void gl_lds16(const void* g, void* lds_base) {
    __builtin_amdgcn_global_load_lds(
        (const __attribute__((address_space(1))) unsigned int*)g,
        (__attribute__((address_space(3))) unsigned int*)lds_base, 16, 0, 0);
}

// ============================================================
// K-1: presplit wa_W1 into bf16 hi/lo global arrays. Unchanged R19.
// ============================================================
__global__ __launch_bounds__(256) void k_split_w1(const float* __restrict__ W1)
{
    const int i = (blockIdx.x * 256 + threadIdx.x) * 4;
    if (i >= 128 * 256) return;
    float4 v = *(const float4*)&W1[i];
    ushort_t h0 = f2bf(v.x), h1 = f2bf(v.y), h2 = f2bf(v.z), h3 = f2bf(v.w);
    *(ushort4*)&g_w1hi[i] = make_ushort4(h0, h1, h2, h3);
    *(ushort4*)&g_w1lo[i] = make_ushort4(
        f2bf(v.x - bf2f(h0)), f2bf(v.y - bf2f(h1)),
        f2bf(v.z - bf2f(h2)), f2bf(v.w - bf2f(h3)));
}

// ============================================================
// K0: vocab input projection via MFMA (split-bf16 3-pass).
// P stored fp16. Unchanged from the 736us config (R9).
// ============================================================
__global__ __launch_bounds__(512, 2) void k_emb_proj(
    const float* __restrict__ emb,
    const float* __restrict__ Wih_f, const float* __restrict__ bih_f, const float* __restrict__ bhh_f,
    const float* __restrict__ Wih_b, const float* __restrict__ bih_b, const float* __restrict__ bhh_b)
{
    constexpr int NT = V / 16;   // 3125
    const int dir = blockIdx.x & 1;
    const int bid = blockIdx.x >> 1;      // 0..EP_NB-1
    const float* Wih = dir ? Wih_b : Wih_f;
    const float* bih = dir ? bih_b : bih_f;
    const float* bhh = dir ? bhh_b : bhh_f;
    _Float16* P = g_P + (size_t)dir * V * 512;

    const int tid  = threadIdx.x;
    const int wv   = tid >> 6;
    const int lane = tid & 63;
    const int l15  = lane & 15;
    const int q    = lane >> 4;

    short8 bhi[4][4], blo[4][4];
    #pragma unroll
    for (int nt = 0; nt < 4; ++nt) {
        const float* wrow = Wih + (size_t)(wv * 64 + nt * 16 + l15) * E;
        #pragma unroll
        for (int kt = 0; kt < 4; ++kt) {
            const float* wp = wrow + kt * 32 + q * 8;
            short8 h8, l8;
            #pragma unroll
            for (int i = 0; i < 8; ++i) {
                float f = wp[i];
                ushort_t hb = f2bf(f);
                h8[i] = (short)hb;
                l8[i] = (short)f2bf(f - bf2f(hb));
            }
            bhi[nt][kt] = h8;
            blo[nt][kt] = l8;
        }
    }

    const int cb = (tid * 4) & 511;
    const int jj = cb >> 2;
    float4 bias4 = make_float4(bih[jj]       + bhh[jj],
                               bih[128 + jj] + bhh[128 + jj],
                               bih[256 + jj] + bhh[256 + jj],
                               bih[384 + jj] + bhh[384 + jj]);

    __shared__ __align__(16) float xs[2][2048];   // raw emb tile, dbuf (16KB)
    __shared__ ushort_t xh[16][136];              // bf16 hi (4.3KB)
    __shared__ ushort_t xl[16][136];              // bf16 lo (4.3KB)
    __shared__ float    os[16][516];              // out staging (33KB)

    int tile = bid;
    if (tile < NT)
        gl_lds16(emb + (size_t)tile * 2048 + wv * 256 + lane * 4, &xs[0][wv * 256]);
    int cur = 0;
    bool first = true;

    for (; tile < NT; tile += EP_NB) {
        if (first) { asm volatile("s_waitcnt vmcnt(0)" ::: "memory"); }
        else       { asm volatile("s_waitcnt vmcnt(4)" ::: "memory"); }
        asm volatile("s_waitcnt lgkmcnt(0)" ::: "memory");
        __builtin_amdgcn_sched_barrier(0);
        __builtin_amdgcn_s_barrier();
        first = false;

        if (tile + EP_NB < NT)
            gl_lds16(emb + (size_t)(tile + EP_NB) * 2048 + wv * 256 + lane * 4,
                     &xs[cur ^ 1][wv * 256]);

        {
            const int idx = tid * 4;
            const int row = idx >> 7, col = idx & 127;
            float4 v = *(const float4*)&xs[cur][idx];
            ushort_t h0 = f2bf(v.x), h1 = f2bf(v.y), h2 = f2bf(v.z), h3 = f2bf(v.w);
            *(ushort4*)&xh[row][col] = make_ushort4(h0, h1, h2, h3);
            *(ushort4*)&xl[row][col] = make_ushort4(
                f2bf(v.x - bf2f(h0)), f2bf(v.y - bf2f(h1)),
                f2bf(v.z - bf2f(h2)), f2bf(v.w - bf2f(h3)));
        }
        asm volatile("s_waitcnt lgkmcnt(0)" ::: "memory");
        __builtin_amdgcn_sched_barrier(0);
        __builtin_amdgcn_s_barrier();

        short8 ahi[4], alo[4];
        #pragma unroll
        for (int kt = 0; kt < 4; ++kt) {
            ahi[kt] = *(const short8*)&xh[l15][kt * 32 + q * 8];
            alo[kt] = *(const short8*)&xl[l15][kt * 32 + q * 8];
        }

        f32x4 acc[4];
        #pragma unroll
        for (int nt = 0; nt < 4; ++nt) acc[nt] = (f32x4){0.f, 0.f, 0.f, 0.f};
        #pragma unroll
        for (int kt = 0; kt < 4; ++kt) {
            #pragma unroll
            for (int nt = 0; nt < 4; ++nt) {
                acc[nt] = __builtin_amdgcn_mfma_f32_16x16x32_bf16(ahi[kt], bhi[nt][kt], acc[nt], 0, 0, 0);
                acc[nt] = __builtin_amdgcn_mfma_f32_16x16x32_bf16(alo[kt], bhi[nt][kt], acc[nt], 0, 0, 0);
                acc[nt] = __builtin_amdgcn_mfma_f32_16x16x32_bf16(ahi[kt], blo[nt][kt], acc[nt], 0, 0, 0);
            }
        }

        #pragma unroll
        for (int nt = 0; nt < 4; ++nt) {
            const int c0 = wv * 64 + nt * 16;
            #pragma unroll
            for (int r = 0; r < 4; ++r) {
                const int c = c0 + l15;
                os[q * 4 + r][((c & 127) << 2) | (c >> 7)] = acc[nt][r];
            }
        }
        asm volatile("s_waitcnt lgkmcnt(0)" ::: "memory");
        __builtin_amdgcn_sched_barrier(0);
        __builtin_amdgcn_s_barrier();

        // stream staging -> P (fp16, 8B per 4 gates; 4 stores/thread)
        const int r0 = tile * 16;
        #pragma unroll
        for (int i = tid * 4; i < 16 * 512; i += 2048) {
            const int row = i >> 9, col = i & 511;
            float4 v = *(const float4*)&os[row][col];
            h16x4 hv;
            hv.x = (_Float16)(v.x + bias4.x);
            hv.y = (_Float16)(v.y + bias4.y);
            hv.z = (_Float16)(v.z + bias4.z);
            hv.w = (_Float16)(v.w + bias4.w);
            *(h16x4*)&P[(size_t)(r0 + row) * 512 + col] = hv;
        }
        cur ^= 1;
    }
}

// ============================================================
// K1: word BiLSTM recurrence via MFMA, split-bf16.
// R22: REVERT to R9 single-buffer schedule (736us best; R10 dbuf
// was neutral->worse). Change: h output stored fp16 (halves the
// 98MB wl_h write stream; recurrence state in LDS stays split-bf16).
// ============================================================
__global__ __launch_bounds__(512, 2) void k_word_lstm(
    const int* __restrict__ ids,
    const float* __restrict__ Whh_f, const float* __restrict__ Whh_b)
{
    const int dir = blockIdx.x & 1;
    const int s0  = (blockIdx.x >> 1) * 32;          // 32 seqs per block
    const float* Whh = dir ? Whh_b : Whh_f;
    const _Float16* Pp = g_P + (size_t)dir * V * 512;

    __shared__ ushort_t sh_hhi[2][2][16][136];       // [buf][unit][row][col]
    __shared__ ushort_t sh_hlo[2][2][16][136];
    __shared__ int      ids_sh[32 * W];
    __shared__ __align__(16) _Float16 pgbuf[8][2][16][64]; // [wave][u][seq][64] 32KB

    const int tid  = threadIdx.x;
    const int wv   = tid >> 6;
    const int lane = tid & 63;
    const int l15  = lane & 15;
    const int q    = lane >> 4;
    const int jc   = wv * 16 + l15;                  // owned hidden col
    const int l7   = lane & 7;                       // col-pair within gather
    const int sq8  = lane >> 3;                      // seq within gather call

    // persistent B-frags: output col c = nt*128 + jc  ->  Whh row c
    short8 bhi[4][4], blo[4][4];
    #pragma unroll
    for (int nt = 0; nt < 4; ++nt) {
        const float* wrow = Whh + (size_t)(nt * 128 + jc) * H;
        #pragma unroll
        for (int kt = 0; kt < 4; ++kt) {
            const float* wp = wrow + kt * 32 + q * 8;
            short8 h8, l8;
            #pragma unroll
            for (int i = 0; i < 8; ++i) {
                float f = wp[i];
                ushort_t hb = f2bf(f);
                h8[i] = (short)hb;
                l8[i] = (short)f2bf(f - bf2f(hb));
            }
            bhi[nt][kt] = h8;
            blo[nt][kt] = l8;
        }
    }

    for (int i = tid; i < 32 * W; i += 512) ids_sh[i] = ids[s0 * W + i];
    for (int i = tid; i < 2 * 2 * 16 * 136; i += 512) {
        (&sh_hhi[0][0][0][0])[i] = 0;
        (&sh_hlo[0][0][0][0])[i] = 0;
    }
    float cst[2][4];
    #pragma unroll
    for (int u = 0; u < 2; ++u)
        #pragma unroll
        for (int r = 0; r < 4; ++r) cst[u][r] = 0.f;
    __syncthreads();

    // prologue: issue gathers for step 0 (4 wave-wide calls)
    {
        const int t0 = dir ? (W - 1) : 0;
        #pragma unroll
        for (int u = 0; u < 2; ++u)
            #pragma unroll
            for (int c = 0; c < 2; ++c) {
                const int sq = c * 8 + sq8;
                const _Float16* gsrc = Pp + (size_t)ids_sh[(u * 16 + sq) * W + t0] * 512
                                          + (wv * 16 + l7 * 2) * 4;
                gl_lds16(gsrc, &pgbuf[wv][u][c * 8][0]);
            }
    }

    for (int st = 0; st < W; ++st) {
        const int t = dir ? (W - 1 - st) : st;
        const int p = st & 1;

        // ---- MFMA on h(t-1) from LDS buf p (zero-init acc, no mem dep) ----
        f32x4 acc[2][4];
        #pragma unroll
        for (int u = 0; u < 2; ++u)
            #pragma unroll
            for (int nt = 0; nt < 4; ++nt) acc[u][nt] = (f32x4){0.f, 0.f, 0.f, 0.f};

        #pragma unroll
        for (int u = 0; u < 2; ++u) {
            const ushort_t* ph = &sh_hhi[p][u][l15][q * 8];
            const ushort_t* pl = &sh_hlo[p][u][l15][q * 8];
            #pragma unroll
            for (int kt = 0; kt < 4; ++kt) {
                short8 ahi = *(const short8*)(ph + kt * 32);
                short8 alo = *(const short8*)(pl + kt * 32);
                #pragma unroll
                for (int nt = 0; nt < 4; ++nt) {
                    acc[u][nt] = __builtin_amdgcn_mfma_f32_16x16x32_bf16(ahi, bhi[nt][kt], acc[u][nt], 0, 0, 0);
                    acc[u][nt] = __builtin_amdgcn_mfma_f32_16x16x32_bf16(alo, bhi[nt][kt], acc[u][nt], 0, 0, 0);
                    acc[u][nt] = __builtin_amdgcn_mfma_f32_16x16x32_bf16(ahi, blo[nt][kt], acc[u][nt], 0, 0, 0);
                }
            }
        }

        // ---- wait for this step's pg prefetch (counted: skip store acks) ----
        if (st == 0) { asm volatile("s_waitcnt vmcnt(0)" ::: "memory"); }
        else         { asm volatile("s_waitcnt vmcnt(8)" ::: "memory"); }
        __builtin_amdgcn_sched_barrier(0);

        // pg readback: 4 fp16 gates per (u,r) at pgbuf[wv][u][s][l15*4]
        float4 pg[2][4];
        #pragma unroll
        for (int u = 0; u < 2; ++u)
            #pragma unroll
            for (int r = 0; r < 4; ++r) {
                const int s = q * 4 + r;
                h16x4 hv = *(const h16x4*)&pgbuf[wv][u][s][l15 * 4];
                pg[u][r] = make_float4((float)hv.x, (float)hv.y, (float)hv.z, (float)hv.w);
            }

        // ensure pg ds_reads landed before slab is overwritten by prefetch
        asm volatile("s_waitcnt lgkmcnt(0)" ::: "memory");
        __builtin_amdgcn_sched_barrier(0);

        // ---- issue prefetch for step st+1 (4 wave-wide calls) ----
        if (st + 1 < W) {
            const int tn = dir ? (W - 2 - st) : st + 1;
            #pragma unroll
            for (int u = 0; u < 2; ++u)
                #pragma unroll
                for (int c = 0; c < 2; ++c) {
                    const int sq = c * 8 + sq8;
                    const _Float16* gsrc = Pp + (size_t)ids_sh[(u * 16 + sq) * W + tn] * 512
                                              + (wv * 16 + l7 * 2) * 4;
                    gl_lds16(gsrc, &pgbuf[wv][u][c * 8][0]);
                }
        }

        // ---- gates fully in-register; h stored fp16 ----
        #pragma unroll
        for (int u = 0; u < 2; ++u) {
            #pragma unroll
            for (int r = 0; r < 4; ++r) {
                const int s = q * 4 + r;
                float gi = acc[u][0][r] + pg[u][r].x;
                float gf = acc[u][1][r] + pg[u][r].y;
                float gg = acc[u][2][r] + pg[u][r].z;
                float go = acc[u][3][r] + pg[u][r].w;
                float c = sigf(gf) * cst[u][r] + sigf(gi) * tanh_fast(gg);
                float h = sigf(go) * tanh_fast(c);
                cst[u][r] = c;
                g_wl_h[((size_t)(s0 + u * 16 + s) * W + t) * 256 + dir * H + jc] = (_Float16)h;
                ushort_t hb = f2bf(h);
                sh_hhi[p ^ 1][u][s][jc] = hb;
                sh_hlo[p ^ 1][u][s][jc] = f2bf(h - bf2f(hb));
            }
        }

        // raw barrier: drain LDS ops only, keep prefetch loads in flight
        asm volatile("s_waitcnt lgkmcnt(0)" ::: "memory");
        __builtin_amdgcn_sched_barrier(0);
        __builtin_amdgcn_s_barrier();
    }
}

// ============================================================
// K2: FUSED word attention (scores + softmax + pool).
// R22: reads wl_h as fp16 (half the bytes); bf16 hi/lo split of
// an fp16 value is exact.
// ============================================================
__global__ __launch_bounds__(256, 2) void k_word_attn(
    const int* __restrict__ ids,
    const float* __restrict__ b1, const float* __restrict__ W2,
    const float* __restrict__ b2)
{
    const int n    = blockIdx.x;
    const int tid  = threadIdx.x;
    const int wv   = tid >> 6;        // 0..3
    const int lane = tid & 63;
    const int l15  = lane & 15;
    const int q    = lane >> 4;

    __shared__ float    hsh[W][256];  // 30 KB
    __shared__ ushort_t xhi[32][264]; // 16.9 KB
    __shared__ ushort_t xlo[32][264];
    __shared__ float    part[4][32];
    __shared__ float    wsh[32];

    short8 bhi[2][8], blo[2][8];
    float  b1n[2], w2n[2];
    #pragma unroll
    for (int ntl = 0; ntl < 2; ++ntl) {
        const int c = (2 * wv + ntl) * 16 + l15;
        #pragma unroll
        for (int kt = 0; kt < 8; ++kt) {
            bhi[ntl][kt] = *(const short8*)&g_w1hi[c * 256 + kt * 32 + q * 8];
            blo[ntl][kt] = *(const short8*)&g_w1lo[c * 256 + kt * 32 + q * 8];
        }
        b1n[ntl] = b1[c];
        w2n[ntl] = W2[c];
    }
    const float b2v = b2[0];

    const _Float16* src = g_wl_h + (size_t)n * W * 256;
    for (int i = tid * 4; i < W * 256; i += 1024) {
        const int row = i >> 8, col = i & 255;
        h16x4 hv4 = *(const h16x4*)&src[i];
        float4 v = make_float4((float)hv4.x, (float)hv4.y, (float)hv4.z, (float)hv4.w);
        *(float4*)&hsh[row][col] = v;
        ushort_t h0 = f2bf(v.x), h1 = f2bf(v.y), h2 = f2bf(v.z), h3 = f2bf(v.w);
        *(ushort4*)&xhi[row][col] = make_ushort4(h0, h1, h2, h3);
        *(ushort4*)&xlo[row][col] = make_ushort4(
            f2bf(v.x - bf2f(h0)), f2bf(v.y - bf2f(h1)),
            f2bf(v.z - bf2f(h2)), f2bf(v.w - bf2f(h3)));
    }
    for (int i = tid; i < 2 * 264; i += 256) {
        (&xhi[30][0])[i] = 0;
        (&xlo[30][0])[i] = 0;
    }
    __syncthreads();

    float vr[2][4];
    #pragma unroll
    for (int rt = 0; rt < 2; ++rt) {
        short8 ahi[8], alo[8];
        #pragma unroll
        for (int kt = 0; kt < 8; ++kt) {
            ahi[kt] = *(const short8*)&xhi[rt * 16 + l15][kt * 32 + q * 8];
            alo[kt] = *(const short8*)&xlo[rt * 16 + l15][kt * 32 + q * 8];
        }
        #pragma unroll
        for (int ntl = 0; ntl < 2; ++ntl) {
            f32x4 acc = (f32x4){0.f, 0.f, 0.f, 0.f};
            #pragma unroll
            for (int kt = 0; kt < 8; ++kt) {
                acc = __builtin_amdgcn_mfma_f32_16x16x32_bf16(ahi[kt], bhi[ntl][kt], acc, 0, 0, 0);
                acc = __builtin_amdgcn_mfma_f32_16x16x32_bf16(alo[kt], bhi[ntl][kt], acc, 0, 0, 0);
                acc = __builtin_amdgcn_mfma_f32_16x16x32_bf16(ahi[kt], blo[ntl][kt], acc, 0, 0, 0);
            }
            #pragma unroll
            for (int r = 0; r < 4; ++r) {
                float u = tanh_fast(acc[r] + b1n[ntl]) * w2n[ntl];
                if (ntl == 0) vr[rt][r] = u; else vr[rt][r] += u;
            }
        }
    }
    #pragma unroll
    for (int rt = 0; rt < 2; ++rt)
        #pragma unroll
        for (int r = 0; r < 4; ++r) {
            float v = vr[rt][r];
            v += __shfl_xor(v, 1, 64);
            v += __shfl_xor(v, 2, 64);
            v += __shfl_xor(v, 4, 64);
            v += __shfl_xor(v, 8, 64);
            vr[rt][r] = v;
        }
    if (l15 == 0) {
        #pragma unroll
        for (int rt = 0; rt < 2; ++rt)
            #pragma unroll
            for (int r = 0; r < 4; ++r)
                part[wv][rt * 16 + q * 4 + r] = vr[rt][r];
    }
    __syncthreads();

    if (tid < 32) {
        const int t = tid;
        float s = b2v + part[0][t] + part[1][t] + part[2][t] + part[3][t];
        bool valid = (t < W) && (ids[n * W + t] != 0);
        wsh[t] = valid ? s : -INFINITY;
    }
    __syncthreads();

    if (tid < 64) {
        float v = (tid < W) ? wsh[tid] : -INFINITY;
        float m = v;
        #pragma unroll
        for (int off = 32; off > 0; off >>= 1) m = fmaxf(m, __shfl_xor(m, off, 64));
        float e = (v == -INFINITY) ? 0.f : __expf(v - m);
        float ssum = e;
        #pragma unroll
        for (int off = 32; off > 0; off >>= 1) ssum += __shfl_xor(ssum, off, 64);
        const float inv = (ssum > 0.f) ? 1.f / ssum : 0.f;
        if (tid < W) wsh[tid] = e * inv;
    }
    __syncthreads();

    float o = 0.f;
    #pragma unroll
    for (int t = 0; t < W; ++t) o += wsh[t] * hsh[t][tid];
    g_sent[(size_t)n * 256 + tid] = o;
}

// ============================================================
// K3: sentence LSTM input projection. Store gate-interleaved. Unchanged.
// ============================================================
__global__ __launch_bounds__(256) void k_sl_gin(
    const float* __restrict__ Wih_f, const float* __restrict__ bih_f, const float* __restrict__ bhh_f,
    const float* __restrict__ Wih_b, const float* __restrict__ bih_b, const float* __restrict__ bhh_b)
{
    const int dir = blockIdx.x & 1;
    const float* Wih = dir ? Wih_b : Wih_f;
    const float* bih = dir ? bih_b : bih_f;
    const float* bhh = dir ? bhh_b : bhh_f;
    float* gin = dir ? g_gin_b : g_gin_f;
    const int r0 = (blockIdx.x >> 1) * NSEQ_G;

    __shared__ float xs[NSEQ_G][256];
    const int tid = threadIdx.x;
    for (int i = tid * 4; i < NSEQ_G * 256; i += 1024)
        *(float4*)&(&xs[0][0])[i] = *(const float4*)&g_sent[(size_t)r0 * 256 + i];
    __syncthreads();

    const int g0 = tid, g1 = tid + 256;
    float acc0[NSEQ_G], acc1[NSEQ_G];
    #pragma unroll
    for (int s = 0; s < NSEQ_G; ++s) { acc0[s] = 0.f; acc1[s] = 0.f; }
    const float* w0 = &Wih[g0 * 256]; const float* w1 = &Wih[g1 * 256];
    for (int k = 0; k < 256; k += 4) {
        float4 wa = *(const float4*)(w0 + k);
        float4 wb = *(const float4*)(w1 + k);
        #pragma unroll
        for (int s = 0; s < NSEQ_G; ++s) {
            float4 xv = *(const float4*)&xs[s][k];
            acc0[s] += dot4(wa, xv);
            acc1[s] += dot4(wb, xv);
        }
    }
    const float bv0 = bih[g0] + bhh[g0];
    const float bv1 = bih[g1] + bhh[g1];
    const int p0 = ((g0 & 127) << 2) | (g0 >> 7);
    const int p1 = ((g1 & 127) << 2) | (g1 >> 7);
    #pragma unroll
    for (int s = 0; s < NSEQ_G; ++s) {
        gin[(size_t)(r0 + s) * 512 + p0] = acc0[s] + bv0;
        gin[(size_t)(r0 + s) * 512 + p1] = acc1[s] + bv1;
    }
}

// ============================================================
// K4: sentence BiLSTM via MFMA col-block recurrence. Unchanged R18.
// ============================================================
__global__ __launch_bounds__(512, 2) void k_sent_lstm(
    const float* __restrict__ Whh_f, const float* __restrict__ Whh_b)
{
    const int dir = blockIdx.x & 1;
    const int s0  = (blockIdx.x >> 1) * 16;          // 16 docs per block
    const float* Whh = dir ? Whh_b : Whh_f;
    const float* gin = dir ? g_gin_b : g_gin_f;

    __shared__ ushort_t sh_hhi[2][16][136];
    __shared__ ushort_t sh_hlo[2][16][136];

    const int tid  = threadIdx.x;
    const int wv   = tid >> 6;
    const int lane = tid & 63;
    const int l15  = lane & 15;
    const int q    = lane >> 4;
    const int jc   = wv * 16 + l15;

    short8 bhi[4][4], blo[4][4];
    #pragma unroll
    for (int nt = 0; nt < 4; ++nt) {
        const float* wrow = Whh + (size_t)(nt * 128 + jc) * H;
        #pragma unroll
        for (int kt = 0; kt < 4; ++kt) {
            const float* wp = wrow + kt * 32 + q * 8;
            short8 h8, l8;
            #pragma unroll
            for (int i = 0; i < 8; ++i) {
                float f = wp[i];
                ushort_t hb = f2bf(f);
                h8[i] = (short)hb;
                l8[i] = (short)f2bf(f - bf2f(hb));
            }
            bhi[nt][kt] = h8;
            blo[nt][kt] = l8;
        }
    }

    for (int i = tid; i < 2 * 16 * 136; i += 512) {
        (&sh_hhi[0][0][0])[i] = 0;
        (&sh_hlo[0][0][0])[i] = 0;
    }
    float cst[4] = {0.f, 0.f, 0.f, 0.f};
    __syncthreads();

    for (int st = 0; st < S; ++st) {
        const int t = dir ? (S - 1 - st) : st;
        const int p = st & 1;

        float4 pg[4];
        #pragma unroll
        for (int r = 0; r < 4; ++r) {
            const int b = s0 + q * 4 + r;
            pg[r] = *(const float4*)(gin + (size_t)(b * S + t) * 512 + jc * 4);
        }

        f32x4 acc[4];
        #pragma unroll
        for (int nt = 0; nt < 4; ++nt) acc[nt] = (f32x4){0.f, 0.f, 0.f, 0.f};
        {
            const ushort_t* ph = &sh_hhi[p][l15][q * 8];
            const ushort_t* pl = &sh_hlo[p][l15][q * 8];
            #pragma unroll
            for (int kt = 0; kt < 4; ++kt) {
                short8 ahi = *(const short8*)(ph + kt * 32);
                short8 alo = *(const short8*)(pl + kt * 32);
                #pragma unroll
                for (int nt = 0; nt < 4; ++nt) {
                    acc[nt] = __builtin_amdgcn_mfma_f32_16x16x32_bf16(ahi, bhi[nt][kt], acc[nt], 0, 0, 0);
                    acc[nt] = __builtin_amdgcn_mfma_f32_16x16x32_bf16(alo, bhi[nt][kt], acc[nt], 0, 0, 0);
                    acc[nt] = __builtin_amdgcn_mfma_f32_16x16x32_bf16(ahi, blo[nt][kt], acc[nt], 0, 0, 0);
                }
            }
        }

        #pragma unroll
        for (int r = 0; r < 4; ++r) {
            const int s = q * 4 + r;
            const int b = s0 + s;
            float gi = acc[0][r] + pg[r].x;
            float gf = acc[1][r] + pg[r].y;
            float gg = acc[2][r] + pg[r].z;
            float go = acc[3][r] + pg[r].w;
            float c = sigf(gf) * cst[r] + sigf(gi) * tanh_fast(gg);
            float h = sigf(go) * tanh_fast(c);
            cst[r] = c;
            g_sl_h[(size_t)(b * S + t) * 256 + dir * H + jc] = h;
            ushort_t hb = f2bf(h);
            sh_hhi[p ^ 1][s][jc] = hb;
            sh_hlo[p ^ 1][s][jc] = f2bf(h - bf2f(hb));
        }
        __syncthreads();
    }
}

// ============================================================
// K5: document attention pool. Wave-parallel softmax. Unchanged.
// ============================================================
template <int T>
__global__ __launch_bounds__(128) void k_attn_pool_doc(
    const int* __restrict__ ids,
    const float* __restrict__ W1, const float* __restrict__ b1,
    const float* __restrict__ W2, const float* __restrict__ b2)
{
    constexpr int TH = T / 2;
    const int n = blockIdx.x;
    __shared__ float hsh[T][256];
    __shared__ float wsh[T];
    const int tid = threadIdx.x;
    const int lane = tid & 63;
    const int wv   = tid >> 6;

    const float* src = g_sl_h + (size_t)n * T * 256;
    for (int i = tid * 4; i < T * 256; i += 512)
        *(float4*)&(&hsh[0][0])[i] = *(const float4*)&src[i];
    __syncthreads();

    const int j0 = lane, j1 = lane + 64;
    const int tbase = wv * TH;
    float acc0[TH], acc1[TH];
    #pragma unroll
    for (int u = 0; u < TH; ++u) { acc0[u] = 0.f; acc1[u] = 0.f; }
    const float* w1a = &W1[j0 * 256];
    const float* w1b = &W1[j1 * 256];
    for (int k = 0; k < 256; k += 4) {
        float4 wa = *(const float4*)(w1a + k);
        float4 wb = *(const float4*)(w1b + k);
        #pragma unroll
        for (int u = 0; u < TH; ++u) {
            float4 hv = *(const float4*)&hsh[tbase + u][k];
            acc0[u] += dot4(wa, hv);
            acc1[u] += dot4(wb, hv);
        }
    }
    const float b1a = b1[j0], b1b = b1[j1];
    const float w2a = W2[j0], w2b = W2[j1];
    #pragma unroll
    for (int u = 0; u < TH; ++u) {
        float v = w2a * tanh_fast(acc0[u] + b1a) + w2b * tanh_fast(acc1[u] + b1b);
        #pragma unroll
        for (int off = 32; off > 0; off >>= 1) v += __shfl_down(v, off, 64);
        if (lane == 0) wsh[tbase + u] = v;
    }
    __syncthreads();

    if (tid < T) {
        bool valid = false;
        const int* ip = &ids[((size_t)n * T + tid) * W];
        for (int w = 0; w < W; ++w) valid |= (ip[w] != 0);
        wsh[tid] = valid ? (wsh[tid] + b2[0]) : -INFINITY;
    }
    __syncthreads();
    if (tid < 64) {
        float v = (tid < T) ? wsh[tid] : -INFINITY;
        float m = v;
        #pragma unroll
        for (int off = 32; off > 0; off >>= 1) m = fmaxf(m, __shfl_xor(m, off, 64));
        float e = (v == -INFINITY) ? 0.f : __expf(v - m);
        float ssum = e;
        #pragma unroll
        for (int off = 32; off > 0; off >>= 1) ssum += __shfl_xor(ssum, off, 64);
        const float inv = (ssum > 0.f) ? 1.f / ssum : 0.f;
        if (tid < T) wsh[tid] = e * inv;
    }
    __syncthreads();

    float o0 = 0.f, o1 = 0.f;
    #pragma unroll
    for (int t = 0; t < T; ++t) {
        float w = wsh[t];
        o0 += w * hsh[t][tid];
        o1 += w * hsh[t][tid + 128];
    }
    g_doc[(size_t)n * 256 + tid] = o0;
    g_doc[(size_t)n * 256 + tid + 128] = o1;
}

// ============================================================
// K6: classifier. Unchanged.
// ============================================================
__global__ __launch_bounds__(128) void k_classifier(
    const float* __restrict__ W1, const float* __restrict__ b1,
    const float* __restrict__ W2, const float* __restrict__ b2,
    float* __restrict__ out)
{
    const int b = blockIdx.x;
    __shared__ float dsh[256];
    __shared__ float hsh[128];
    const int tid = threadIdx.x;
    if (tid < 64) *(float4*)&dsh[tid * 4] = *(const float4*)&g_doc[(size_t)b * 256 + tid * 4];
    __syncthreads();
    float acc = 0.f;
    const float* w1p = &W1[tid * 256];
    for (int k = 0; k < 256; k += 4) {
        float4 w4 = *(const float4*)(w1p + k);
        float4 d4 = *(const float4*)&dsh[k];
        acc += dot4(w4, d4);
    }
    hsh[tid] = fmaxf(acc + b1[tid], 0.f);
    __syncthreads();
    if (tid < 3) {
        float a = b2[tid];
        const float* w2p = &W2[tid * 128];
        for (int j = 0; j < 128; ++j) a += w2p[j] * hsh[j];
        out[b * 3 + tid] = a;
    }
}

// ============================================================
extern "C" void kernel_launch(void* const* d_in, const int* in_sizes, int n_in,
                              void* d_out, int out_size, void* d_ws, size_t ws_size,
                              hipStream_t stream) {
    const int*   ids      = (const int*)d_in[0];
    const float* emb      = (const float*)d_in[1];
    const float* wl_Wih_f = (const float*)d_in[2];
    const float* wl_Whh_f = (const float*)d_in[3];
    const float* wl_bih_f = (const float*)d_in[4];
    const float* wl_bhh_f = (const float*)d_in[5];
    const float* wl_Wih_b = (const float*)d_in[6];
    const float* wl_Whh_b = (const float*)d_in[7];
    const float* wl_bih_b = (const float*)d_in[8];
    const float* wl_bhh_b = (const float*)d_in[9];
    const float* sl_Wih_f = (const float*)d_in[10];
    const float* sl_Whh_f = (const float*)d_in[11];
    const float* sl_bih_f = (const float*)d_in[12];
    const float* sl_bhh_f = (const float*)d_in[13];
    const float* sl_Wih_b = (const float*)d_in[14];
    const float* sl_Whh_b = (const float*)d_in[15];
    const float* sl_bih_b = (const float*)d_in[16];
    const float* sl_bhh_b = (const float*)d_in[17];
    const float* wa_W1 = (const float*)d_in[18];
    const float* wa_b1 = (const float*)d_in[19];
    const float* wa_W2 = (const float*)d_in[20];
    const float* wa_b2 = (const float*)d_in[21];
    const float* sa_W1 = (const float*)d_in[22];
    const float* sa_b1 = (const float*)d_in[23];
    const float* sa_W2 = (const float*)d_in[24];
    const float* sa_b2 = (const float*)d_in[25];
    const float* cl_W1 = (const float*)d_in[26];
    const float* cl_b1 = (const float*)d_in[27];
    const float* cl_W2 = (const float*)d_in[28];
    const float* cl_b2 = (const float*)d_in[29];

    k_split_w1<<<32, 256, 0, stream>>>(wa_W1);

    k_emb_proj<<<EP_NB * 2, 512, 0, stream>>>(
        emb, wl_Wih_f, wl_bih_f, wl_bhh_f, wl_Wih_b, wl_bih_b, wl_bhh_b);

    k_word_lstm<<<(NW / 32) * 2, 512, 0, stream>>>(ids, wl_Whh_f, wl_Whh_b);

    k_word_attn<<<NW, 256, 0, stream>>>(ids, wa_b1, wa_W2, wa_b2);

    k_sl_gin<<<NW / NSEQ_G * 2, 256, 0, stream>>>(
        sl_Wih_f, sl_bih_f, sl_bhh_f, sl_Wih_b, sl_bih_b, sl_bhh_b);

    k_sent_lstm<<<(B / 16) * 2, 512, 0, stream>>>(sl_Whh_f, sl_Whh_b);

    k_attn_pool_doc<S><<<B, 128, 0, stream>>>(ids, sa_W1, sa_b1, sa_W2, sa_b2);

    k_classifier<<<B, 128, 0, stream>>>(cl_W1, cl_b1, cl_W2, cl_b2, (float*)d_out);
}

// Round 12
// 667.268 us; speedup vs baseline: 1.1078x; 1.0987x over previous
//
#include <hip/hip_runtime.h>
#include <math.h>

typedef unsigned short ushort_t;
typedef __attribute__((ext_vector_type(8))) short short8;
typedef __attribute__((ext_vector_type(8))) _Float16 half8;
typedef __attribute__((ext_vector_type(4))) float f32x4;
typedef __attribute__((ext_vector_type(4))) _Float16 h16x4;

// ---- dims ----
constexpr int B  = 64;
constexpr int S  = 50;
constexpr int W  = 30;
constexpr int E  = 128;
constexpr int H  = 128;
constexpr int NW = B * S;      // 3200 word sequences
constexpr int V  = 50000;      // vocab
constexpr int NSEQ_G = 8;      // rows per block in sl gin GEMM
constexpr int EP_NB = 256;     // emb_proj blocks per dir (grid-stride, 2/CU)

// ---- intermediates as module-scope device globals ----
// g_P GATE-INTERLEAVED fp16 (R20); g_wl_h fp16 (R22).
__device__ _Float16 g_P  [(size_t)2 * V * 512];   // 102.4 MB
__device__ _Float16 g_wl_h[(size_t)NW * W * 256]; // 49.2 MB
__device__ float g_sent [(size_t)NW * 256];       // 3.28 MB
__device__ float g_gin_f[(size_t)NW * 512];       // 6.55 MB (gate-interleaved)
__device__ float g_gin_b[(size_t)NW * 512];       // 6.55 MB (gate-interleaved)
__device__ float g_sl_h [(size_t)B * S * 256];    // 3.28 MB
__device__ float g_doc  [(size_t)B * 256];        // 64 KB
__device__ ushort_t g_w1hi[128 * 256];            // wa_W1 bf16 hi (presplit)
__device__ ushort_t g_w1lo[128 * 256];            // wa_W1 bf16 lo (presplit)

// ---- helpers ----
__device__ __forceinline__ float sigf(float x) { return 1.0f / (1.0f + __expf(-x)); }
__device__ __forceinline__ float tanh_fast(float x) { return 2.0f / (1.0f + __expf(-2.0f * x)) - 1.0f; }
__device__ __forceinline__ float dot4(float4 a, float4 b) {
    return fmaf(a.x, b.x, fmaf(a.y, b.y, fmaf(a.z, b.z, a.w * b.w)));
}
__device__ __forceinline__ float bf2f(ushort_t u) {
    union { float f; unsigned int i; } v; v.i = ((unsigned int)u) << 16; return v.f;
}
__device__ __forceinline__ ushort_t f2bf(float f) {
    union { float f; unsigned int i; } v; v.f = f;
    unsigned int r = v.i + 0x7fffu + ((v.i >> 16) & 1u);
    return (ushort_t)(r >> 16);
}
// async global->LDS, 16B per lane; lds dest = uniform base + lane*16
__device__ __forceinline__ void gl_lds16(const void* g, void* lds_base) {
    __builtin_amdgcn_global_load_lds(
        (const __attribute__((address_space(1))) unsigned int*)g,
        (__attribute__((address_space(3))) unsigned int*)lds_base, 16, 0, 0);
}

// ============================================================
// K-1: presplit wa_W1 into bf16 hi/lo global arrays. Unchanged R19.
// ============================================================
__global__ __launch_bounds__(256) void k_split_w1(const float* __restrict__ W1)
{
    const int i = (blockIdx.x * 256 + threadIdx.x) * 4;
    if (i >= 128 * 256) return;
    float4 v = *(const float4*)&W1[i];
    ushort_t h0 = f2bf(v.x), h1 = f2bf(v.y), h2 = f2bf(v.z), h3 = f2bf(v.w);
    *(ushort4*)&g_w1hi[i] = make_ushort4(h0, h1, h2, h3);
    *(ushort4*)&g_w1lo[i] = make_ushort4(
        f2bf(v.x - bf2f(h0)), f2bf(v.y - bf2f(h1)),
        f2bf(v.z - bf2f(h2)), f2bf(v.w - bf2f(h3)));
}

// ============================================================
// K0: vocab input projection via MFMA (split-bf16 3-pass).
// P stored fp16. Unchanged from the 733us config.
// ============================================================
__global__ __launch_bounds__(512, 2) void k_emb_proj(
    const float* __restrict__ emb,
    const float* __restrict__ Wih_f, const float* __restrict__ bih_f, const float* __restrict__ bhh_f,
    const float* __restrict__ Wih_b, const float* __restrict__ bih_b, const float* __restrict__ bhh_b)
{
    constexpr int NT = V / 16;   // 3125
    const int dir = blockIdx.x & 1;
    const int bid = blockIdx.x >> 1;      // 0..EP_NB-1
    const float* Wih = dir ? Wih_b : Wih_f;
    const float* bih = dir ? bih_b : bih_f;
    const float* bhh = dir ? bhh_b : bhh_f;
    _Float16* P = g_P + (size_t)dir * V * 512;

    const int tid  = threadIdx.x;
    const int wv   = tid >> 6;
    const int lane = tid & 63;
    const int l15  = lane & 15;
    const int q    = lane >> 4;

    short8 bhi[4][4], blo[4][4];
    #pragma unroll
    for (int nt = 0; nt < 4; ++nt) {
        const float* wrow = Wih + (size_t)(wv * 64 + nt * 16 + l15) * E;
        #pragma unroll
        for (int kt = 0; kt < 4; ++kt) {
            const float* wp = wrow + kt * 32 + q * 8;
            short8 h8, l8;
            #pragma unroll
            for (int i = 0; i < 8; ++i) {
                float f = wp[i];
                ushort_t hb = f2bf(f);
                h8[i] = (short)hb;
                l8[i] = (short)f2bf(f - bf2f(hb));
            }
            bhi[nt][kt] = h8;
            blo[nt][kt] = l8;
        }
    }

    const int cb = (tid * 4) & 511;
    const int jj = cb >> 2;
    float4 bias4 = make_float4(bih[jj]       + bhh[jj],
                               bih[128 + jj] + bhh[128 + jj],
                               bih[256 + jj] + bhh[256 + jj],
                               bih[384 + jj] + bhh[384 + jj]);

    __shared__ __align__(16) float xs[2][2048];   // raw emb tile, dbuf (16KB)
    __shared__ ushort_t xh[16][136];              // bf16 hi (4.3KB)
    __shared__ ushort_t xl[16][136];              // bf16 lo (4.3KB)
    __shared__ float    os[16][516];              // out staging (33KB)

    int tile = bid;
    if (tile < NT)
        gl_lds16(emb + (size_t)tile * 2048 + wv * 256 + lane * 4, &xs[0][wv * 256]);
    int cur = 0;
    bool first = true;

    for (; tile < NT; tile += EP_NB) {
        if (first) { asm volatile("s_waitcnt vmcnt(0)" ::: "memory"); }
        else       { asm volatile("s_waitcnt vmcnt(4)" ::: "memory"); }
        asm volatile("s_waitcnt lgkmcnt(0)" ::: "memory");
        __builtin_amdgcn_sched_barrier(0);
        __builtin_amdgcn_s_barrier();
        first = false;

        if (tile + EP_NB < NT)
            gl_lds16(emb + (size_t)(tile + EP_NB) * 2048 + wv * 256 + lane * 4,
                     &xs[cur ^ 1][wv * 256]);

        {
            const int idx = tid * 4;
            const int row = idx >> 7, col = idx & 127;
            float4 v = *(const float4*)&xs[cur][idx];
            ushort_t h0 = f2bf(v.x), h1 = f2bf(v.y), h2 = f2bf(v.z), h3 = f2bf(v.w);
            *(ushort4*)&xh[row][col] = make_ushort4(h0, h1, h2, h3);
            *(ushort4*)&xl[row][col] = make_ushort4(
                f2bf(v.x - bf2f(h0)), f2bf(v.y - bf2f(h1)),
                f2bf(v.z - bf2f(h2)), f2bf(v.w - bf2f(h3)));
        }
        asm volatile("s_waitcnt lgkmcnt(0)" ::: "memory");
        __builtin_amdgcn_sched_barrier(0);
        __builtin_amdgcn_s_barrier();

        short8 ahi[4], alo[4];
        #pragma unroll
        for (int kt = 0; kt < 4; ++kt) {
            ahi[kt] = *(const short8*)&xh[l15][kt * 32 + q * 8];
            alo[kt] = *(const short8*)&xl[l15][kt * 32 + q * 8];
        }

        f32x4 acc[4];
        #pragma unroll
        for (int nt = 0; nt < 4; ++nt) acc[nt] = (f32x4){0.f, 0.f, 0.f, 0.f};
        #pragma unroll
        for (int kt = 0; kt < 4; ++kt) {
            #pragma unroll
            for (int nt = 0; nt < 4; ++nt) {
                acc[nt] = __builtin_amdgcn_mfma_f32_16x16x32_bf16(ahi[kt], bhi[nt][kt], acc[nt], 0, 0, 0);
                acc[nt] = __builtin_amdgcn_mfma_f32_16x16x32_bf16(alo[kt], bhi[nt][kt], acc[nt], 0, 0, 0);
                acc[nt] = __builtin_amdgcn_mfma_f32_16x16x32_bf16(ahi[kt], blo[nt][kt], acc[nt], 0, 0, 0);
            }
        }

        #pragma unroll
        for (int nt = 0; nt < 4; ++nt) {
            const int c0 = wv * 64 + nt * 16;
            #pragma unroll
            for (int r = 0; r < 4; ++r) {
                const int c = c0 + l15;
                os[q * 4 + r][((c & 127) << 2) | (c >> 7)] = acc[nt][r];
            }
        }
        asm volatile("s_waitcnt lgkmcnt(0)" ::: "memory");
        __builtin_amdgcn_sched_barrier(0);
        __builtin_amdgcn_s_barrier();

        // stream staging -> P (fp16, 8B per 4 gates; 4 stores/thread)
        const int r0 = tile * 16;
        #pragma unroll
        for (int i = tid * 4; i < 16 * 512; i += 2048) {
            const int row = i >> 9, col = i & 511;
            float4 v = *(const float4*)&os[row][col];
            h16x4 hv;
            hv.x = (_Float16)(v.x + bias4.x);
            hv.y = (_Float16)(v.y + bias4.y);
            hv.z = (_Float16)(v.z + bias4.z);
            hv.w = (_Float16)(v.w + bias4.w);
            *(h16x4*)&P[(size_t)(r0 + row) * 512 + col] = hv;
        }
        cur ^= 1;
    }
}

// ============================================================
// K1: word BiLSTM recurrence via MFMA.
// R23: SINGLE-PASS fp16 MFMA (was split-bf16 3-pass): 32 MFMAs/step
// (was 96), sh_h is plain fp16 (half LDS, ONE convert per h instead
// of 2xf2bf+sub), Whh B-frags fp16 (64 VGPR, was 128). Schedule,
// gather layout and counted vmcnt(8) identical to the 733us config.
// ============================================================
__global__ __launch_bounds__(512, 2) void k_word_lstm(
    const int* __restrict__ ids,
    const float* __restrict__ Whh_f, const float* __restrict__ Whh_b)
{
    const int dir = blockIdx.x & 1;
    const int s0  = (blockIdx.x >> 1) * 32;          // 32 seqs per block
    const float* Whh = dir ? Whh_b : Whh_f;
    const _Float16* Pp = g_P + (size_t)dir * V * 512;

    __shared__ _Float16 sh_h[2][2][16][136];         // [buf][unit][row][col] 17.4KB
    __shared__ int      ids_sh[32 * W];
    __shared__ __align__(16) _Float16 pgbuf[8][2][16][64]; // [wave][u][seq][64] 32KB

    const int tid  = threadIdx.x;
    const int wv   = tid >> 6;
    const int lane = tid & 63;
    const int l15  = lane & 15;
    const int q    = lane >> 4;
    const int jc   = wv * 16 + l15;                  // owned hidden col
    const int l7   = lane & 7;                       // col-pair within gather
    const int sq8  = lane >> 3;                      // seq within gather call

    // persistent B-frags (fp16): output col c = nt*128 + jc -> Whh row c
    half8 bh[4][4];
    #pragma unroll
    for (int nt = 0; nt < 4; ++nt) {
        const float* wrow = Whh + (size_t)(nt * 128 + jc) * H;
        #pragma unroll
        for (int kt = 0; kt < 4; ++kt) {
            const float* wp = wrow + kt * 32 + q * 8;
            half8 h8;
            #pragma unroll
            for (int i = 0; i < 8; ++i) h8[i] = (_Float16)wp[i];
            bh[nt][kt] = h8;
        }
    }

    for (int i = tid; i < 32 * W; i += 512) ids_sh[i] = ids[s0 * W + i];
    for (int i = tid; i < 2 * 2 * 16 * 136; i += 512)
        (&sh_h[0][0][0][0])[i] = (_Float16)0.f;
    float cst[2][4];
    #pragma unroll
    for (int u = 0; u < 2; ++u)
        #pragma unroll
        for (int r = 0; r < 4; ++r) cst[u][r] = 0.f;
    __syncthreads();

    // prologue: issue gathers for step 0 (4 wave-wide calls)
    {
        const int t0 = dir ? (W - 1) : 0;
        #pragma unroll
        for (int u = 0; u < 2; ++u)
            #pragma unroll
            for (int c = 0; c < 2; ++c) {
                const int sq = c * 8 + sq8;
                const _Float16* gsrc = Pp + (size_t)ids_sh[(u * 16 + sq) * W + t0] * 512
                                          + (wv * 16 + l7 * 2) * 4;
                gl_lds16(gsrc, &pgbuf[wv][u][c * 8][0]);
            }
    }

    for (int st = 0; st < W; ++st) {
        const int t = dir ? (W - 1 - st) : st;
        const int p = st & 1;

        // ---- MFMA on h(t-1) from LDS buf p (zero-init acc, no mem dep) ----
        f32x4 acc[2][4];
        #pragma unroll
        for (int u = 0; u < 2; ++u)
            #pragma unroll
            for (int nt = 0; nt < 4; ++nt) acc[u][nt] = (f32x4){0.f, 0.f, 0.f, 0.f};

        #pragma unroll
        for (int u = 0; u < 2; ++u) {
            const _Float16* ph = &sh_h[p][u][l15][q * 8];
            #pragma unroll
            for (int kt = 0; kt < 4; ++kt) {
                half8 ah = *(const half8*)(ph + kt * 32);
                #pragma unroll
                for (int nt = 0; nt < 4; ++nt)
                    acc[u][nt] = __builtin_amdgcn_mfma_f32_16x16x32_f16(ah, bh[nt][kt], acc[u][nt], 0, 0, 0);
            }
        }

        // ---- wait for this step's pg prefetch (counted: skip store acks) ----
        if (st == 0) { asm volatile("s_waitcnt vmcnt(0)" ::: "memory"); }
        else         { asm volatile("s_waitcnt vmcnt(8)" ::: "memory"); }
        __builtin_amdgcn_sched_barrier(0);

        // pg readback: 4 fp16 gates per (u,r) at pgbuf[wv][u][s][l15*4]
        float4 pg[2][4];
        #pragma unroll
        for (int u = 0; u < 2; ++u)
            #pragma unroll
            for (int r = 0; r < 4; ++r) {
                const int s = q * 4 + r;
                h16x4 hv = *(const h16x4*)&pgbuf[wv][u][s][l15 * 4];
                pg[u][r] = make_float4((float)hv.x, (float)hv.y, (float)hv.z, (float)hv.w);
            }

        // ensure pg ds_reads landed before slab is overwritten by prefetch
        asm volatile("s_waitcnt lgkmcnt(0)" ::: "memory");
        __builtin_amdgcn_sched_barrier(0);

        // ---- issue prefetch for step st+1 (4 wave-wide calls) ----
        if (st + 1 < W) {
            const int tn = dir ? (W - 2 - st) : st + 1;
            #pragma unroll
            for (int u = 0; u < 2; ++u)
                #pragma unroll
                for (int c = 0; c < 2; ++c) {
                    const int sq = c * 8 + sq8;
                    const _Float16* gsrc = Pp + (size_t)ids_sh[(u * 16 + sq) * W + tn] * 512
                                              + (wv * 16 + l7 * 2) * 4;
                    gl_lds16(gsrc, &pgbuf[wv][u][c * 8][0]);
                }
        }

        // ---- gates fully in-register; h stored fp16 (single convert) ----
        #pragma unroll
        for (int u = 0; u < 2; ++u) {
            #pragma unroll
            for (int r = 0; r < 4; ++r) {
                const int s = q * 4 + r;
                float gi = acc[u][0][r] + pg[u][r].x;
                float gf = acc[u][1][r] + pg[u][r].y;
                float gg = acc[u][2][r] + pg[u][r].z;
                float go = acc[u][3][r] + pg[u][r].w;
                float c = sigf(gf) * cst[u][r] + sigf(gi) * tanh_fast(gg);
                float h = sigf(go) * tanh_fast(c);
                cst[u][r] = c;
                _Float16 hh = (_Float16)h;
                g_wl_h[((size_t)(s0 + u * 16 + s) * W + t) * 256 + dir * H + jc] = hh;
                sh_h[p ^ 1][u][s][jc] = hh;
            }
        }

        // raw barrier: drain LDS ops only, keep prefetch loads in flight
        asm volatile("s_waitcnt lgkmcnt(0)" ::: "memory");
        __builtin_amdgcn_sched_barrier(0);
        __builtin_amdgcn_s_barrier();
    }
}

// ============================================================
// K2: FUSED word attention (scores + softmax + pool). Unchanged R22.
// ============================================================
__global__ __launch_bounds__(256, 2) void k_word_attn(
    const int* __restrict__ ids,
    const float* __restrict__ b1, const float* __restrict__ W2,
    const float* __restrict__ b2)
{
    const int n    = blockIdx.x;
    const int tid  = threadIdx.x;
    const int wv   = tid >> 6;        // 0..3
    const int lane = tid & 63;
    const int l15  = lane & 15;
    const int q    = lane >> 4;

    __shared__ float    hsh[W][256];  // 30 KB
    __shared__ ushort_t xhi[32][264]; // 16.9 KB
    __shared__ ushort_t xlo[32][264];
    __shared__ float    part[4][32];
    __shared__ float    wsh[32];

    short8 bhi[2][8], blo[2][8];
    float  b1n[2], w2n[2];
    #pragma unroll
    for (int ntl = 0; ntl < 2; ++ntl) {
        const int c = (2 * wv + ntl) * 16 + l15;
        #pragma unroll
        for (int kt = 0; kt < 8; ++kt) {
            bhi[ntl][kt] = *(const short8*)&g_w1hi[c * 256 + kt * 32 + q * 8];
            blo[ntl][kt] = *(const short8*)&g_w1lo[c * 256 + kt * 32 + q * 8];
        }
        b1n[ntl] = b1[c];
        w2n[ntl] = W2[c];
    }
    const float b2v = b2[0];

    const _Float16* src = g_wl_h + (size_t)n * W * 256;
    for (int i = tid * 4; i < W * 256; i += 1024) {
        const int row = i >> 8, col = i & 255;
        h16x4 hv4 = *(const h16x4*)&src[i];
        float4 v = make_float4((float)hv4.x, (float)hv4.y, (float)hv4.z, (float)hv4.w);
        *(float4*)&hsh[row][col] = v;
        ushort_t h0 = f2bf(v.x), h1 = f2bf(v.y), h2 = f2bf(v.z), h3 = f2bf(v.w);
        *(ushort4*)&xhi[row][col] = make_ushort4(h0, h1, h2, h3);
        *(ushort4*)&xlo[row][col] = make_ushort4(
            f2bf(v.x - bf2f(h0)), f2bf(v.y - bf2f(h1)),
            f2bf(v.z - bf2f(h2)), f2bf(v.w - bf2f(h3)));
    }
    for (int i = tid; i < 2 * 264; i += 256) {
        (&xhi[30][0])[i] = 0;
        (&xlo[30][0])[i] = 0;
    }
    __syncthreads();

    float vr[2][4];
    #pragma unroll
    for (int rt = 0; rt < 2; ++rt) {
        short8 ahi[8], alo[8];
        #pragma unroll
        for (int kt = 0; kt < 8; ++kt) {
            ahi[kt] = *(const short8*)&xhi[rt * 16 + l15][kt * 32 + q * 8];
            alo[kt] = *(const short8*)&xlo[rt * 16 + l15][kt * 32 + q * 8];
        }
        #pragma unroll
        for (int ntl = 0; ntl < 2; ++ntl) {
            f32x4 acc = (f32x4){0.f, 0.f, 0.f, 0.f};
            #pragma unroll
            for (int kt = 0; kt < 8; ++kt) {
                acc = __builtin_amdgcn_mfma_f32_16x16x32_bf16(ahi[kt], bhi[ntl][kt], acc, 0, 0, 0);
                acc = __builtin_amdgcn_mfma_f32_16x16x32_bf16(alo[kt], bhi[ntl][kt], acc, 0, 0, 0);
                acc = __builtin_amdgcn_mfma_f32_16x16x32_bf16(ahi[kt], blo[ntl][kt], acc, 0, 0, 0);
            }
            #pragma unroll
            for (int r = 0; r < 4; ++r) {
                float u = tanh_fast(acc[r] + b1n[ntl]) * w2n[ntl];
                if (ntl == 0) vr[rt][r] = u; else vr[rt][r] += u;
            }
        }
    }
    #pragma unroll
    for (int rt = 0; rt < 2; ++rt)
        #pragma unroll
        for (int r = 0; r < 4; ++r) {
            float v = vr[rt][r];
            v += __shfl_xor(v, 1, 64);
            v += __shfl_xor(v, 2, 64);
            v += __shfl_xor(v, 4, 64);
            v += __shfl_xor(v, 8, 64);
            vr[rt][r] = v;
        }
    if (l15 == 0) {
        #pragma unroll
        for (int rt = 0; rt < 2; ++rt)
            #pragma unroll
            for (int r = 0; r < 4; ++r)
                part[wv][rt * 16 + q * 4 + r] = vr[rt][r];
    }
    __syncthreads();

    if (tid < 32) {
        const int t = tid;
        float s = b2v + part[0][t] + part[1][t] + part[2][t] + part[3][t];
        bool valid = (t < W) && (ids[n * W + t] != 0);
        wsh[t] = valid ? s : -INFINITY;
    }
    __syncthreads();

    if (tid < 64) {
        float v = (tid < W) ? wsh[tid] : -INFINITY;
        float m = v;
        #pragma unroll
        for (int off = 32; off > 0; off >>= 1) m = fmaxf(m, __shfl_xor(m, off, 64));
        float e = (v == -INFINITY) ? 0.f : __expf(v - m);
        float ssum = e;
        #pragma unroll
        for (int off = 32; off > 0; off >>= 1) ssum += __shfl_xor(ssum, off, 64);
        const float inv = (ssum > 0.f) ? 1.f / ssum : 0.f;
        if (tid < W) wsh[tid] = e * inv;
    }
    __syncthreads();

    float o = 0.f;
    #pragma unroll
    for (int t = 0; t < W; ++t) o += wsh[t] * hsh[t][tid];
    g_sent[(size_t)n * 256 + tid] = o;
}

// ============================================================
// K3: sentence LSTM input projection. Store gate-interleaved. Unchanged.
// ============================================================
__global__ __launch_bounds__(256) void k_sl_gin(
    const float* __restrict__ Wih_f, const float* __restrict__ bih_f, const float* __restrict__ bhh_f,
    const float* __restrict__ Wih_b, const float* __restrict__ bih_b, const float* __restrict__ bhh_b)
{
    const int dir = blockIdx.x & 1;
    const float* Wih = dir ? Wih_b : Wih_f;
    const float* bih = dir ? bih_b : bih_f;
    const float* bhh = dir ? bhh_b : bhh_f;
    float* gin = dir ? g_gin_b : g_gin_f;
    const int r0 = (blockIdx.x >> 1) * NSEQ_G;

    __shared__ float xs[NSEQ_G][256];
    const int tid = threadIdx.x;
    for (int i = tid * 4; i < NSEQ_G * 256; i += 1024)
        *(float4*)&(&xs[0][0])[i] = *(const float4*)&g_sent[(size_t)r0 * 256 + i];
    __syncthreads();

    const int g0 = tid, g1 = tid + 256;
    float acc0[NSEQ_G], acc1[NSEQ_G];
    #pragma unroll
    for (int s = 0; s < NSEQ_G; ++s) { acc0[s] = 0.f; acc1[s] = 0.f; }
    const float* w0 = &Wih[g0 * 256]; const float* w1 = &Wih[g1 * 256];
    for (int k = 0; k < 256; k += 4) {
        float4 wa = *(const float4*)(w0 + k);
        float4 wb = *(const float4*)(w1 + k);
        #pragma unroll
        for (int s = 0; s < NSEQ_G; ++s) {
            float4 xv = *(const float4*)&xs[s][k];
            acc0[s] += dot4(wa, xv);
            acc1[s] += dot4(wb, xv);
        }
    }
    const float bv0 = bih[g0] + bhh[g0];
    const float bv1 = bih[g1] + bhh[g1];
    const int p0 = ((g0 & 127) << 2) | (g0 >> 7);
    const int p1 = ((g1 & 127) << 2) | (g1 >> 7);
    #pragma unroll
    for (int s = 0; s < NSEQ_G; ++s) {
        gin[(size_t)(r0 + s) * 512 + p0] = acc0[s] + bv0;
        gin[(size_t)(r0 + s) * 512 + p1] = acc1[s] + bv1;
    }
}

// ============================================================
// K4: sentence BiLSTM via MFMA col-block recurrence.
// R23: single-pass fp16 MFMA (16 MFMAs/step, was 48); sh_h fp16.
// ============================================================
__global__ __launch_bounds__(512, 2) void k_sent_lstm(
    const float* __restrict__ Whh_f, const float* __restrict__ Whh_b)
{
    const int dir = blockIdx.x & 1;
    const int s0  = (blockIdx.x >> 1) * 16;          // 16 docs per block
    const float* Whh = dir ? Whh_b : Whh_f;
    const float* gin = dir ? g_gin_b : g_gin_f;

    __shared__ _Float16 sh_h[2][16][136];            // 8.7KB

    const int tid  = threadIdx.x;
    const int wv   = tid >> 6;
    const int lane = tid & 63;
    const int l15  = lane & 15;
    const int q    = lane >> 4;
    const int jc   = wv * 16 + l15;

    half8 bh[4][4];
    #pragma unroll
    for (int nt = 0; nt < 4; ++nt) {
        const float* wrow = Whh + (size_t)(nt * 128 + jc) * H;
        #pragma unroll
        for (int kt = 0; kt < 4; ++kt) {
            const float* wp = wrow + kt * 32 + q * 8;
            half8 h8;
            #pragma unroll
            for (int i = 0; i < 8; ++i) h8[i] = (_Float16)wp[i];
            bh[nt][kt] = h8;
        }
    }

    for (int i = tid; i < 2 * 16 * 136; i += 512)
        (&sh_h[0][0][0])[i] = (_Float16)0.f;
    float cst[4] = {0.f, 0.f, 0.f, 0.f};
    __syncthreads();

    for (int st = 0; st < S; ++st) {
        const int t = dir ? (S - 1 - st) : st;
        const int p = st & 1;

        float4 pg[4];
        #pragma unroll
        for (int r = 0; r < 4; ++r) {
            const int b = s0 + q * 4 + r;
            pg[r] = *(const float4*)(gin + (size_t)(b * S + t) * 512 + jc * 4);
        }

        f32x4 acc[4];
        #pragma unroll
        for (int nt = 0; nt < 4; ++nt) acc[nt] = (f32x4){0.f, 0.f, 0.f, 0.f};
        {
            const _Float16* ph = &sh_h[p][l15][q * 8];
            #pragma unroll
            for (int kt = 0; kt < 4; ++kt) {
                half8 ah = *(const half8*)(ph + kt * 32);
                #pragma unroll
                for (int nt = 0; nt < 4; ++nt)
                    acc[nt] = __builtin_amdgcn_mfma_f32_16x16x32_f16(ah, bh[nt][kt], acc[nt], 0, 0, 0);
            }
        }

        #pragma unroll
        for (int r = 0; r < 4; ++r) {
            const int s = q * 4 + r;
            const int b = s0 + s;
            float gi = acc[0][r] + pg[r].x;
            float gf = acc[1][r] + pg[r].y;
            float gg = acc[2][r] + pg[r].z;
            float go = acc[3][r] + pg[r].w;
            float c = sigf(gf) * cst[r] + sigf(gi) * tanh_fast(gg);
            float h = sigf(go) * tanh_fast(c);
            cst[r] = c;
            g_sl_h[(size_t)(b * S + t) * 256 + dir * H + jc] = h;
            sh_h[p ^ 1][s][jc] = (_Float16)h;
        }
        __syncthreads();
    }
}

// ============================================================
// K5: document attention pool. Wave-parallel softmax. Unchanged.
// ============================================================
template <int T>
__global__ __launch_bounds__(128) void k_attn_pool_doc(
    const int* __restrict__ ids,
    const float* __restrict__ W1, const float* __restrict__ b1,
    const float* __restrict__ W2, const float* __restrict__ b2)
{
    constexpr int TH = T / 2;
    const int n = blockIdx.x;
    __shared__ float hsh[T][256];
    __shared__ float wsh[T];
    const int tid = threadIdx.x;
    const int lane = tid & 63;
    const int wv   = tid >> 6;

    const float* src = g_sl_h + (size_t)n * T * 256;
    for (int i = tid * 4; i < T * 256; i += 512)
        *(float4*)&(&hsh[0][0])[i] = *(const float4*)&src[i];
    __syncthreads();

    const int j0 = lane, j1 = lane + 64;
    const int tbase = wv * TH;
    float acc0[TH], acc1[TH];
    #pragma unroll
    for (int u = 0; u < TH; ++u) { acc0[u] = 0.f; acc1[u] = 0.f; }
    const float* w1a = &W1[j0 * 256];
    const float* w1b = &W1[j1 * 256];
    for (int k = 0; k < 256; k += 4) {
        float4 wa = *(const float4*)(w1a + k);
        float4 wb = *(const float4*)(w1b + k);
        #pragma unroll
        for (int u = 0; u < TH; ++u) {
            float4 hv = *(const float4*)&hsh[tbase + u][k];
            acc0[u] += dot4(wa, hv);
            acc1[u] += dot4(wb, hv);
        }
    }
    const float b1a = b1[j0], b1b = b1[j1];
    const float w2a = W2[j0], w2b = W2[j1];
    #pragma unroll
    for (int u = 0; u < TH; ++u) {
        float v = w2a * tanh_fast(acc0[u] + b1a) + w2b * tanh_fast(acc1[u] + b1b);
        #pragma unroll
        for (int off = 32; off > 0; off >>= 1) v += __shfl_down(v, off, 64);
        if (lane == 0) wsh[tbase + u] = v;
    }
    __syncthreads();

    if (tid < T) {
        bool valid = false;
        const int* ip = &ids[((size_t)n * T + tid) * W];
        for (int w = 0; w < W; ++w) valid |= (ip[w] != 0);
        wsh[tid] = valid ? (wsh[tid] + b2[0]) : -INFINITY;
    }
    __syncthreads();
    if (tid < 64) {
        float v = (tid < T) ? wsh[tid] : -INFINITY;
        float m = v;
        #pragma unroll
        for (int off = 32; off > 0; off >>= 1) m = fmaxf(m, __shfl_xor(m, off, 64));
        float e = (v == -INFINITY) ? 0.f : __expf(v - m);
        float ssum = e;
        #pragma unroll
        for (int off = 32; off > 0; off >>= 1) ssum += __shfl_xor(ssum, off, 64);
        const float inv = (ssum > 0.f) ? 1.f / ssum : 0.f;
        if (tid < T) wsh[tid] = e * inv;
    }
    __syncthreads();

    float o0 = 0.f, o1 = 0.f;
    #pragma unroll
    for (int t = 0; t < T; ++t) {
        float w = wsh[t];
        o0 += w * hsh[t][tid];
        o1 += w * hsh[t][tid + 128];
    }
    g_doc[(size_t)n * 256 + tid] = o0;
    g_doc[(size_t)n * 256 + tid + 128] = o1;
}

// ============================================================
// K6: classifier. Unchanged.
// ============================================================
__global__ __launch_bounds__(128) void k_classifier(
    const float* __restrict__ W1, const float* __restrict__ b1,
    const float* __restrict__ W2, const float* __restrict__ b2,
    float* __restrict__ out)
{
    const int b = blockIdx.x;
    __shared__ float dsh[256];
    __shared__ float hsh[128];
    const int tid = threadIdx.x;
    if (tid < 64) *(float4*)&dsh[tid * 4] = *(const float4*)&g_doc[(size_t)b * 256 + tid * 4];
    __syncthreads();
    float acc = 0.f;
    const float* w1p = &W1[tid * 256];
    for (int k = 0; k < 256; k += 4) {
        float4 w4 = *(const float4*)(w1p + k);
        float4 d4 = *(const float4*)&dsh[k];
        acc += dot4(w4, d4);
    }
    hsh[tid] = fmaxf(acc + b1[tid], 0.f);
    __syncthreads();
    if (tid < 3) {
        float a = b2[tid];
        const float* w2p = &W2[tid * 128];
        for (int j = 0; j < 128; ++j) a += w2p[j] * hsh[j];
        out[b * 3 + tid] = a;
    }
}

// ============================================================
extern "C" void kernel_launch(void* const* d_in, const int* in_sizes, int n_in,
                              void* d_out, int out_size, void* d_ws, size_t ws_size,
                              hipStream_t stream) {
    const int*   ids      = (const int*)d_in[0];
    const float* emb      = (const float*)d_in[1];
    const float* wl_Wih_f = (const float*)d_in[2];
    const float* wl_Whh_f = (const float*)d_in[3];
    const float* wl_bih_f = (const float*)d_in[4];
    const float* wl_bhh_f = (const float*)d_in[5];
    const float* wl_Wih_b = (const float*)d_in[6];
    const float* wl_Whh_b = (const float*)d_in[7];
    const float* wl_bih_b = (const float*)d_in[8];
    const float* wl_bhh_b = (const float*)d_in[9];
    const float* sl_Wih_f = (const float*)d_in[10];
    const float* sl_Whh_f = (const float*)d_in[11];
    const float* sl_bih_f = (const float*)d_in[12];
    const float* sl_bhh_f = (const float*)d_in[13];
    const float* sl_Wih_b = (const float*)d_in[14];
    const float* sl_Whh_b = (const float*)d_in[15];
    const float* sl_bih_b = (const float*)d_in[16];
    const float* sl_bhh_b = (const float*)d_in[17];
    const float* wa_W1 = (const float*)d_in[18];
    const float* wa_b1 = (const float*)d_in[19];
    const float* wa_W2 = (const float*)d_in[20];
    const float* wa_b2 = (const float*)d_in[21];
    const float* sa_W1 = (const float*)d_in[22];
    const float* sa_b1 = (const float*)d_in[23];
    const float* sa_W2 = (const float*)d_in[24];
    const float* sa_b2 = (const float*)d_in[25];
    const float* cl_W1 = (const float*)d_in[26];
    const float* cl_b1 = (const float*)d_in[27];
    const float* cl_W2 = (const float*)d_in[28];
    const float* cl_b2 = (const float*)d_in[29];

    k_split_w1<<<32, 256, 0, stream>>>(wa_W1);

    k_emb_proj<<<EP_NB * 2, 512, 0, stream>>>(
        emb, wl_Wih_f, wl_bih_f, wl_bhh_f, wl_Wih_b, wl_bih_b, wl_bhh_b);

    k_word_lstm<<<(NW / 32) * 2, 512, 0, stream>>>(ids, wl_Whh_f, wl_Whh_b);

    k_word_attn<<<NW, 256, 0, stream>>>(ids, wa_b1, wa_W2, wa_b2);

    k_sl_gin<<<NW / NSEQ_G * 2, 256, 0, stream>>>(
        sl_Wih_f, sl_bih_f, sl_bhh_f, sl_Wih_b, sl_bih_b, sl_bhh_b);

    k_sent_lstm<<<(B / 16) * 2, 512, 0, stream>>>(sl_Whh_f, sl_Whh_b);

    k_attn_pool_doc<S><<<B, 128, 0, stream>>>(ids, sa_W1, sa_b1, sa_W2, sa_b2);

    k_classifier<<<B, 128, 0, stream>>>(cl_W1, cl_b1, cl_W2, cl_b2, (float*)d_out);
}

// Round 13
// 572.277 us; speedup vs baseline: 1.2917x; 1.1660x over previous
//
#include <hip/hip_runtime.h>
#include <math.h>

typedef unsigned short ushort_t;
typedef __attribute__((ext_vector_type(8))) short short8;
typedef __attribute__((ext_vector_type(8))) _Float16 half8;
typedef __attribute__((ext_vector_type(4))) float f32x4;
typedef __attribute__((ext_vector_type(4))) _Float16 h16x4;

// ---- dims ----
constexpr int B  = 64;
constexpr int S  = 50;
constexpr int W  = 30;
constexpr int E  = 128;
constexpr int H  = 128;
constexpr int NW = B * S;      // 3200 word sequences
constexpr int V  = 50000;      // vocab
constexpr int NSEQ_G = 8;      // rows per block in sl gin GEMM
constexpr int EP_NB = 256;     // emb_proj blocks per dir (grid-stride, 2/CU)

// ---- intermediates as module-scope device globals ----
__device__ _Float16 g_P  [(size_t)2 * V * 512];   // 102.4 MB (gate-interleaved)
__device__ _Float16 g_wl_h[(size_t)NW * W * 256]; // 49.2 MB
__device__ float g_sent [(size_t)NW * 256];       // 3.28 MB
__device__ float g_gin_f[(size_t)NW * 512];       // 6.55 MB (gate-interleaved)
__device__ float g_gin_b[(size_t)NW * 512];       // 6.55 MB (gate-interleaved)
__device__ float g_sl_h [(size_t)B * S * 256];    // 3.28 MB
__device__ float g_doc  [(size_t)B * 256];        // 64 KB
__device__ _Float16 g_w1h[128 * 256];             // wa_W1 fp16 (presplit)

// ---- helpers ----
__device__ __forceinline__ float sigf(float x) { return 1.0f / (1.0f + __expf(-x)); }
__device__ __forceinline__ float tanh_fast(float x) { return 2.0f / (1.0f + __expf(-2.0f * x)) - 1.0f; }
__device__ __forceinline__ float dot4(float4 a, float4 b) {
    return fmaf(a.x, b.x, fmaf(a.y, b.y, fmaf(a.z, b.z, a.w * b.w)));
}
// async global->LDS, 16B per lane; lds dest = uniform base + lane*16
__device__ __forceinline__ void gl_lds16(const void* g, void* lds_base) {
    __builtin_amdgcn_global_load_lds(
        (const __attribute__((address_space(1))) unsigned int*)g,
        (__attribute__((address_space(3))) unsigned int*)lds_base, 16, 0, 0);
}

// ============================================================
// K-1: presplit wa_W1 to fp16. R24: single array (was bf16 hi/lo).
// ============================================================
__global__ __launch_bounds__(256) void k_split_w1(const float* __restrict__ W1)
{
    const int i = (blockIdx.x * 256 + threadIdx.x) * 4;
    if (i >= 128 * 256) return;
    float4 v = *(const float4*)&W1[i];
    h16x4 h;
    h.x = (_Float16)v.x; h.y = (_Float16)v.y;
    h.z = (_Float16)v.z; h.w = (_Float16)v.w;
    *(h16x4*)&g_w1h[i] = h;
}

// ============================================================
// K0: vocab input projection.
// R24: SINGLE-PASS fp16 MFMA (16/tile, was 48 split-bf16) +
// single fp16 tile convert (4 cvt/thread, was 12 f2bf+sub).
// Schedule/staging/P-write identical to the 667us config.
// ============================================================
__global__ __launch_bounds__(512, 2) void k_emb_proj(
    const float* __restrict__ emb,
    const float* __restrict__ Wih_f, const float* __restrict__ bih_f, const float* __restrict__ bhh_f,
    const float* __restrict__ Wih_b, const float* __restrict__ bih_b, const float* __restrict__ bhh_b)
{
    constexpr int NT = V / 16;   // 3125
    const int dir = blockIdx.x & 1;
    const int bid = blockIdx.x >> 1;      // 0..EP_NB-1
    const float* Wih = dir ? Wih_b : Wih_f;
    const float* bih = dir ? bih_b : bih_f;
    const float* bhh = dir ? bhh_b : bhh_f;
    _Float16* P = g_P + (size_t)dir * V * 512;

    const int tid  = threadIdx.x;
    const int wv   = tid >> 6;
    const int lane = tid & 63;
    const int l15  = lane & 15;
    const int q    = lane >> 4;

    // persistent fp16 B-frags (64 VGPR)
    half8 bh[4][4];
    #pragma unroll
    for (int nt = 0; nt < 4; ++nt) {
        const float* wrow = Wih + (size_t)(wv * 64 + nt * 16 + l15) * E;
        #pragma unroll
        for (int kt = 0; kt < 4; ++kt) {
            const float* wp = wrow + kt * 32 + q * 8;
            half8 h8;
            #pragma unroll
            for (int i = 0; i < 8; ++i) h8[i] = (_Float16)wp[i];
            bh[nt][kt] = h8;
        }
    }

    const int cb = (tid * 4) & 511;
    const int jj = cb >> 2;
    float4 bias4 = make_float4(bih[jj]       + bhh[jj],
                               bih[128 + jj] + bhh[128 + jj],
                               bih[256 + jj] + bhh[256 + jj],
                               bih[384 + jj] + bhh[384 + jj]);

    __shared__ __align__(16) float xs[2][2048];   // raw emb tile, dbuf (16KB)
    __shared__ _Float16 xh16[16][136];            // fp16 tile (4.3KB)
    __shared__ float    os[16][516];              // out staging (33KB)

    int tile = bid;
    if (tile < NT)
        gl_lds16(emb + (size_t)tile * 2048 + wv * 256 + lane * 4, &xs[0][wv * 256]);
    int cur = 0;
    bool first = true;

    for (; tile < NT; tile += EP_NB) {
        if (first) { asm volatile("s_waitcnt vmcnt(0)" ::: "memory"); }
        else       { asm volatile("s_waitcnt vmcnt(4)" ::: "memory"); }
        asm volatile("s_waitcnt lgkmcnt(0)" ::: "memory");
        __builtin_amdgcn_sched_barrier(0);
        __builtin_amdgcn_s_barrier();
        first = false;

        if (tile + EP_NB < NT)
            gl_lds16(emb + (size_t)(tile + EP_NB) * 2048 + wv * 256 + lane * 4,
                     &xs[cur ^ 1][wv * 256]);

        // convert tile to fp16 ONCE (4 cvt per thread)
        {
            const int idx = tid * 4;
            const int row = idx >> 7, col = idx & 127;
            float4 v = *(const float4*)&xs[cur][idx];
            h16x4 h;
            h.x = (_Float16)v.x; h.y = (_Float16)v.y;
            h.z = (_Float16)v.z; h.w = (_Float16)v.w;
            *(h16x4*)&xh16[row][col] = h;
        }
        asm volatile("s_waitcnt lgkmcnt(0)" ::: "memory");
        __builtin_amdgcn_sched_barrier(0);
        __builtin_amdgcn_s_barrier();

        half8 ah[4];
        #pragma unroll
        for (int kt = 0; kt < 4; ++kt)
            ah[kt] = *(const half8*)&xh16[l15][kt * 32 + q * 8];

        f32x4 acc[4];
        #pragma unroll
        for (int nt = 0; nt < 4; ++nt) acc[nt] = (f32x4){0.f, 0.f, 0.f, 0.f};
        #pragma unroll
        for (int kt = 0; kt < 4; ++kt)
            #pragma unroll
            for (int nt = 0; nt < 4; ++nt)
                acc[nt] = __builtin_amdgcn_mfma_f32_16x16x32_f16(ah[kt], bh[nt][kt], acc[nt], 0, 0, 0);

        #pragma unroll
        for (int nt = 0; nt < 4; ++nt) {
            const int c0 = wv * 64 + nt * 16;
            #pragma unroll
            for (int r = 0; r < 4; ++r) {
                const int c = c0 + l15;
                os[q * 4 + r][((c & 127) << 2) | (c >> 7)] = acc[nt][r];
            }
        }
        asm volatile("s_waitcnt lgkmcnt(0)" ::: "memory");
        __builtin_amdgcn_sched_barrier(0);
        __builtin_amdgcn_s_barrier();

        // stream staging -> P (fp16, 8B per 4 gates; 4 stores/thread)
        const int r0 = tile * 16;
        #pragma unroll
        for (int i = tid * 4; i < 16 * 512; i += 2048) {
            const int row = i >> 9, col = i & 511;
            float4 v = *(const float4*)&os[row][col];
            h16x4 hv;
            hv.x = (_Float16)(v.x + bias4.x);
            hv.y = (_Float16)(v.y + bias4.y);
            hv.z = (_Float16)(v.z + bias4.z);
            hv.w = (_Float16)(v.w + bias4.w);
            *(h16x4*)&P[(size_t)(r0 + row) * 512 + col] = hv;
        }
        cur ^= 1;
    }
}

// ============================================================
// K1: word BiLSTM recurrence, single-pass fp16 MFMA. Unchanged R23.
// ============================================================
__global__ __launch_bounds__(512, 2) void k_word_lstm(
    const int* __restrict__ ids,
    const float* __restrict__ Whh_f, const float* __restrict__ Whh_b)
{
    const int dir = blockIdx.x & 1;
    const int s0  = (blockIdx.x >> 1) * 32;          // 32 seqs per block
    const float* Whh = dir ? Whh_b : Whh_f;
    const _Float16* Pp = g_P + (size_t)dir * V * 512;

    __shared__ _Float16 sh_h[2][2][16][136];         // [buf][unit][row][col] 17.4KB
    __shared__ int      ids_sh[32 * W];
    __shared__ __align__(16) _Float16 pgbuf[8][2][16][64]; // [wave][u][seq][64] 32KB

    const int tid  = threadIdx.x;
    const int wv   = tid >> 6;
    const int lane = tid & 63;
    const int l15  = lane & 15;
    const int q    = lane >> 4;
    const int jc   = wv * 16 + l15;                  // owned hidden col
    const int l7   = lane & 7;                       // col-pair within gather
    const int sq8  = lane >> 3;                      // seq within gather call

    // persistent B-frags (fp16): output col c = nt*128 + jc -> Whh row c
    half8 bh[4][4];
    #pragma unroll
    for (int nt = 0; nt < 4; ++nt) {
        const float* wrow = Whh + (size_t)(nt * 128 + jc) * H;
        #pragma unroll
        for (int kt = 0; kt < 4; ++kt) {
            const float* wp = wrow + kt * 32 + q * 8;
            half8 h8;
            #pragma unroll
            for (int i = 0; i < 8; ++i) h8[i] = (_Float16)wp[i];
            bh[nt][kt] = h8;
        }
    }

    for (int i = tid; i < 32 * W; i += 512) ids_sh[i] = ids[s0 * W + i];
    for (int i = tid; i < 2 * 2 * 16 * 136; i += 512)
        (&sh_h[0][0][0][0])[i] = (_Float16)0.f;
    float cst[2][4];
    #pragma unroll
    for (int u = 0; u < 2; ++u)
        #pragma unroll
        for (int r = 0; r < 4; ++r) cst[u][r] = 0.f;
    __syncthreads();

    // prologue: issue gathers for step 0 (4 wave-wide calls)
    {
        const int t0 = dir ? (W - 1) : 0;
        #pragma unroll
        for (int u = 0; u < 2; ++u)
            #pragma unroll
            for (int c = 0; c < 2; ++c) {
                const int sq = c * 8 + sq8;
                const _Float16* gsrc = Pp + (size_t)ids_sh[(u * 16 + sq) * W + t0] * 512
                                          + (wv * 16 + l7 * 2) * 4;
                gl_lds16(gsrc, &pgbuf[wv][u][c * 8][0]);
            }
    }

    for (int st = 0; st < W; ++st) {
        const int t = dir ? (W - 1 - st) : st;
        const int p = st & 1;

        // ---- MFMA on h(t-1) from LDS buf p (zero-init acc, no mem dep) ----
        f32x4 acc[2][4];
        #pragma unroll
        for (int u = 0; u < 2; ++u)
            #pragma unroll
            for (int nt = 0; nt < 4; ++nt) acc[u][nt] = (f32x4){0.f, 0.f, 0.f, 0.f};

        #pragma unroll
        for (int u = 0; u < 2; ++u) {
            const _Float16* ph = &sh_h[p][u][l15][q * 8];
            #pragma unroll
            for (int kt = 0; kt < 4; ++kt) {
                half8 ah = *(const half8*)(ph + kt * 32);
                #pragma unroll
                for (int nt = 0; nt < 4; ++nt)
                    acc[u][nt] = __builtin_amdgcn_mfma_f32_16x16x32_f16(ah, bh[nt][kt], acc[u][nt], 0, 0, 0);
            }
        }

        // ---- wait for this step's pg prefetch (counted: skip store acks) ----
        if (st == 0) { asm volatile("s_waitcnt vmcnt(0)" ::: "memory"); }
        else         { asm volatile("s_waitcnt vmcnt(8)" ::: "memory"); }
        __builtin_amdgcn_sched_barrier(0);

        // pg readback: 4 fp16 gates per (u,r) at pgbuf[wv][u][s][l15*4]
        float4 pg[2][4];
        #pragma unroll
        for (int u = 0; u < 2; ++u)
            #pragma unroll
            for (int r = 0; r < 4; ++r) {
                const int s = q * 4 + r;
                h16x4 hv = *(const h16x4*)&pgbuf[wv][u][s][l15 * 4];
                pg[u][r] = make_float4((float)hv.x, (float)hv.y, (float)hv.z, (float)hv.w);
            }

        // ensure pg ds_reads landed before slab is overwritten by prefetch
        asm volatile("s_waitcnt lgkmcnt(0)" ::: "memory");
        __builtin_amdgcn_sched_barrier(0);

        // ---- issue prefetch for step st+1 (4 wave-wide calls) ----
        if (st + 1 < W) {
            const int tn = dir ? (W - 2 - st) : st + 1;
            #pragma unroll
            for (int u = 0; u < 2; ++u)
                #pragma unroll
                for (int c = 0; c < 2; ++c) {
                    const int sq = c * 8 + sq8;
                    const _Float16* gsrc = Pp + (size_t)ids_sh[(u * 16 + sq) * W + tn] * 512
                                              + (wv * 16 + l7 * 2) * 4;
                    gl_lds16(gsrc, &pgbuf[wv][u][c * 8][0]);
                }
        }

        // ---- gates fully in-register; h stored fp16 (single convert) ----
        #pragma unroll
        for (int u = 0; u < 2; ++u) {
            #pragma unroll
            for (int r = 0; r < 4; ++r) {
                const int s = q * 4 + r;
                float gi = acc[u][0][r] + pg[u][r].x;
                float gf = acc[u][1][r] + pg[u][r].y;
                float gg = acc[u][2][r] + pg[u][r].z;
                float go = acc[u][3][r] + pg[u][r].w;
                float c = sigf(gf) * cst[u][r] + sigf(gi) * tanh_fast(gg);
                float h = sigf(go) * tanh_fast(c);
                cst[u][r] = c;
                _Float16 hh = (_Float16)h;
                g_wl_h[((size_t)(s0 + u * 16 + s) * W + t) * 256 + dir * H + jc] = hh;
                sh_h[p ^ 1][u][s][jc] = hh;
            }
        }

        // raw barrier: drain LDS ops only, keep prefetch loads in flight
        asm volatile("s_waitcnt lgkmcnt(0)" ::: "memory");
        __builtin_amdgcn_sched_barrier(0);
        __builtin_amdgcn_s_barrier();
    }
}

// ============================================================
// K2: FUSED word attention (scores + softmax + pool).
// R24: single-pass fp16 MFMA (32/block, was 96). wl_h is already
// fp16 -> staged with ZERO conversion; W1 fp16 from g_w1h.
// ============================================================
__global__ __launch_bounds__(256, 2) void k_word_attn(
    const int* __restrict__ ids,
    const float* __restrict__ b1, const float* __restrict__ W2,
    const float* __restrict__ b2)
{
    const int n    = blockIdx.x;
    const int tid  = threadIdx.x;
    const int wv   = tid >> 6;        // 0..3
    const int lane = tid & 63;
    const int l15  = lane & 15;
    const int q    = lane >> 4;

    __shared__ float    hsh[W][256];  // 30 KB (fp32 copy for pooling)
    __shared__ _Float16 xh16[32][264];// fp16 tile (16.9 KB)
    __shared__ float    part[4][32];
    __shared__ float    wsh[32];

    // persistent fp16 B-frags: cols c = (2*wv+ntl)*16 + l15
    half8 bh[2][8];
    float b1n[2], w2n[2];
    #pragma unroll
    for (int ntl = 0; ntl < 2; ++ntl) {
        const int c = (2 * wv + ntl) * 16 + l15;
        #pragma unroll
        for (int kt = 0; kt < 8; ++kt)
            bh[ntl][kt] = *(const half8*)&g_w1h[c * 256 + kt * 32 + q * 8];
        b1n[ntl] = b1[c];
        w2n[ntl] = W2[c];
    }
    const float b2v = b2[0];

    // stage h: fp16 pass-through + fp32 copy for pooling
    const _Float16* src = g_wl_h + (size_t)n * W * 256;
    for (int i = tid * 4; i < W * 256; i += 1024) {
        const int row = i >> 8, col = i & 255;
        h16x4 hv4 = *(const h16x4*)&src[i];
        *(h16x4*)&xh16[row][col] = hv4;
        float4 v = make_float4((float)hv4.x, (float)hv4.y, (float)hv4.z, (float)hv4.w);
        *(float4*)&hsh[row][col] = v;
    }
    // zero pad rows 30,31
    for (int i = tid; i < 2 * 264; i += 256)
        (&xh16[30][0])[i] = (_Float16)0.f;
    __syncthreads();

    // scores via fp16 MFMA: 2 row-tiles x 2 col-tiles per wave
    float vr[2][4];
    #pragma unroll
    for (int rt = 0; rt < 2; ++rt) {
        half8 ah[8];
        #pragma unroll
        for (int kt = 0; kt < 8; ++kt)
            ah[kt] = *(const half8*)&xh16[rt * 16 + l15][kt * 32 + q * 8];
        #pragma unroll
        for (int ntl = 0; ntl < 2; ++ntl) {
            f32x4 acc = (f32x4){0.f, 0.f, 0.f, 0.f};
            #pragma unroll
            for (int kt = 0; kt < 8; ++kt)
                acc = __builtin_amdgcn_mfma_f32_16x16x32_f16(ah[kt], bh[ntl][kt], acc, 0, 0, 0);
            #pragma unroll
            for (int r = 0; r < 4; ++r) {
                float u = tanh_fast(acc[r] + b1n[ntl]) * w2n[ntl];
                if (ntl == 0) vr[rt][r] = u; else vr[rt][r] += u;
            }
        }
    }
    #pragma unroll
    for (int rt = 0; rt < 2; ++rt)
        #pragma unroll
        for (int r = 0; r < 4; ++r) {
            float v = vr[rt][r];
            v += __shfl_xor(v, 1, 64);
            v += __shfl_xor(v, 2, 64);
            v += __shfl_xor(v, 4, 64);
            v += __shfl_xor(v, 8, 64);
            vr[rt][r] = v;
        }
    if (l15 == 0) {
        #pragma unroll
        for (int rt = 0; rt < 2; ++rt)
            #pragma unroll
            for (int r = 0; r < 4; ++r)
                part[wv][rt * 16 + q * 4 + r] = vr[rt][r];
    }
    __syncthreads();

    if (tid < 32) {
        const int t = tid;
        float s = b2v + part[0][t] + part[1][t] + part[2][t] + part[3][t];
        bool valid = (t < W) && (ids[n * W + t] != 0);
        wsh[t] = valid ? s : -INFINITY;
    }
    __syncthreads();

    if (tid < 64) {
        float v = (tid < W) ? wsh[tid] : -INFINITY;
        float m = v;
        #pragma unroll
        for (int off = 32; off > 0; off >>= 1) m = fmaxf(m, __shfl_xor(m, off, 64));
        float e = (v == -INFINITY) ? 0.f : __expf(v - m);
        float ssum = e;
        #pragma unroll
        for (int off = 32; off > 0; off >>= 1) ssum += __shfl_xor(ssum, off, 64);
        const float inv = (ssum > 0.f) ? 1.f / ssum : 0.f;
        if (tid < W) wsh[tid] = e * inv;
    }
    __syncthreads();

    float o = 0.f;
    #pragma unroll
    for (int t = 0; t < W; ++t) o += wsh[t] * hsh[t][tid];
    g_sent[(size_t)n * 256 + tid] = o;
}

// ============================================================
// K3: sentence LSTM input projection. Store gate-interleaved. Unchanged.
// ============================================================
__global__ __launch_bounds__(256) void k_sl_gin(
    const float* __restrict__ Wih_f, const float* __restrict__ bih_f, const float* __restrict__ bhh_f,
    const float* __restrict__ Wih_b, const float* __restrict__ bih_b, const float* __restrict__ bhh_b)
{
    const int dir = blockIdx.x & 1;
    const float* Wih = dir ? Wih_b : Wih_f;
    const float* bih = dir ? bih_b : bih_f;
    const float* bhh = dir ? bhh_b : bhh_f;
    float* gin = dir ? g_gin_b : g_gin_f;
    const int r0 = (blockIdx.x >> 1) * NSEQ_G;

    __shared__ float xs[NSEQ_G][256];
    const int tid = threadIdx.x;
    for (int i = tid * 4; i < NSEQ_G * 256; i += 1024)
        *(float4*)&(&xs[0][0])[i] = *(const float4*)&g_sent[(size_t)r0 * 256 + i];
    __syncthreads();

    const int g0 = tid, g1 = tid + 256;
    float acc0[NSEQ_G], acc1[NSEQ_G];
    #pragma unroll
    for (int s = 0; s < NSEQ_G; ++s) { acc0[s] = 0.f; acc1[s] = 0.f; }
    const float* w0 = &Wih[g0 * 256]; const float* w1 = &Wih[g1 * 256];
    for (int k = 0; k < 256; k += 4) {
        float4 wa = *(const float4*)(w0 + k);
        float4 wb = *(const float4*)(w1 + k);
        #pragma unroll
        for (int s = 0; s < NSEQ_G; ++s) {
            float4 xv = *(const float4*)&xs[s][k];
            acc0[s] += dot4(wa, xv);
            acc1[s] += dot4(wb, xv);
        }
    }
    const float bv0 = bih[g0] + bhh[g0];
    const float bv1 = bih[g1] + bhh[g1];
    const int p0 = ((g0 & 127) << 2) | (g0 >> 7);
    const int p1 = ((g1 & 127) << 2) | (g1 >> 7);
    #pragma unroll
    for (int s = 0; s < NSEQ_G; ++s) {
        gin[(size_t)(r0 + s) * 512 + p0] = acc0[s] + bv0;
        gin[(size_t)(r0 + s) * 512 + p1] = acc1[s] + bv1;
    }
}

// ============================================================
// K4: sentence BiLSTM, single-pass fp16 MFMA. Unchanged R23.
// ============================================================
__global__ __launch_bounds__(512, 2) void k_sent_lstm(
    const float* __restrict__ Whh_f, const float* __restrict__ Whh_b)
{
    const int dir = blockIdx.x & 1;
    const int s0  = (blockIdx.x >> 1) * 16;          // 16 docs per block
    const float* Whh = dir ? Whh_b : Whh_f;
    const float* gin = dir ? g_gin_b : g_gin_f;

    __shared__ _Float16 sh_h[2][16][136];            // 8.7KB

    const int tid  = threadIdx.x;
    const int wv   = tid >> 6;
    const int lane = tid & 63;
    const int l15  = lane & 15;
    const int q    = lane >> 4;
    const int jc   = wv * 16 + l15;

    half8 bh[4][4];
    #pragma unroll
    for (int nt = 0; nt < 4; ++nt) {
        const float* wrow = Whh + (size_t)(nt * 128 + jc) * H;
        #pragma unroll
        for (int kt = 0; kt < 4; ++kt) {
            const float* wp = wrow + kt * 32 + q * 8;
            half8 h8;
            #pragma unroll
            for (int i = 0; i < 8; ++i) h8[i] = (_Float16)wp[i];
            bh[nt][kt] = h8;
        }
    }

    for (int i = tid; i < 2 * 16 * 136; i += 512)
        (&sh_h[0][0][0])[i] = (_Float16)0.f;
    float cst[4] = {0.f, 0.f, 0.f, 0.f};
    __syncthreads();

    for (int st = 0; st < S; ++st) {
        const int t = dir ? (S - 1 - st) : st;
        const int p = st & 1;

        float4 pg[4];
        #pragma unroll
        for (int r = 0; r < 4; ++r) {
            const int b = s0 + q * 4 + r;
            pg[r] = *(const float4*)(gin + (size_t)(b * S + t) * 512 + jc * 4);
        }

        f32x4 acc[4];
        #pragma unroll
        for (int nt = 0; nt < 4; ++nt) acc[nt] = (f32x4){0.f, 0.f, 0.f, 0.f};
        {
            const _Float16* ph = &sh_h[p][l15][q * 8];
            #pragma unroll
            for (int kt = 0; kt < 4; ++kt) {
                half8 ah = *(const half8*)(ph + kt * 32);
                #pragma unroll
                for (int nt = 0; nt < 4; ++nt)
                    acc[nt] = __builtin_amdgcn_mfma_f32_16x16x32_f16(ah, bh[nt][kt], acc[nt], 0, 0, 0);
            }
        }

        #pragma unroll
        for (int r = 0; r < 4; ++r) {
            const int s = q * 4 + r;
            const int b = s0 + s;
            float gi = acc[0][r] + pg[r].x;
            float gf = acc[1][r] + pg[r].y;
            float gg = acc[2][r] + pg[r].z;
            float go = acc[3][r] + pg[r].w;
            float c = sigf(gf) * cst[r] + sigf(gi) * tanh_fast(gg);
            float h = sigf(go) * tanh_fast(c);
            cst[r] = c;
            g_sl_h[(size_t)(b * S + t) * 256 + dir * H + jc] = h;
            sh_h[p ^ 1][s][jc] = (_Float16)h;
        }
        __syncthreads();
    }
}

// ============================================================
// K5: document attention pool. Wave-parallel softmax. Unchanged.
// ============================================================
template <int T>
__global__ __launch_bounds__(128) void k_attn_pool_doc(
    const int* __restrict__ ids,
    const float* __restrict__ W1, const float* __restrict__ b1,
    const float* __restrict__ W2, const float* __restrict__ b2)
{
    constexpr int TH = T / 2;
    const int n = blockIdx.x;
    __shared__ float hsh[T][256];
    __shared__ float wsh[T];
    const int tid = threadIdx.x;
    const int lane = tid & 63;
    const int wv   = tid >> 6;

    const float* src = g_sl_h + (size_t)n * T * 256;
    for (int i = tid * 4; i < T * 256; i += 512)
        *(float4*)&(&hsh[0][0])[i] = *(const float4*)&src[i];
    __syncthreads();

    const int j0 = lane, j1 = lane + 64;
    const int tbase = wv * TH;
    float acc0[TH], acc1[TH];
    #pragma unroll
    for (int u = 0; u < TH; ++u) { acc0[u] = 0.f; acc1[u] = 0.f; }
    const float* w1a = &W1[j0 * 256];
    const float* w1b = &W1[j1 * 256];
    for (int k = 0; k < 256; k += 4) {
        float4 wa = *(const float4*)(w1a + k);
        float4 wb = *(const float4*)(w1b + k);
        #pragma unroll
        for (int u = 0; u < TH; ++u) {
            float4 hv = *(const float4*)&hsh[tbase + u][k];
            acc0[u] += dot4(wa, hv);
            acc1[u] += dot4(wb, hv);
        }
    }
    const float b1a = b1[j0], b1b = b1[j1];
    const float w2a = W2[j0], w2b = W2[j1];
    #pragma unroll
    for (int u = 0; u < TH; ++u) {
        float v = w2a * tanh_fast(acc0[u] + b1a) + w2b * tanh_fast(acc1[u] + b1b);
        #pragma unroll
        for (int off = 32; off > 0; off >>= 1) v += __shfl_down(v, off, 64);
        if (lane == 0) wsh[tbase + u] = v;
    }
    __syncthreads();

    if (tid < T) {
        bool valid = false;
        const int* ip = &ids[((size_t)n * T + tid) * W];
        for (int w = 0; w < W; ++w) valid |= (ip[w] != 0);
        wsh[tid] = valid ? (wsh[tid] + b2[0]) : -INFINITY;
    }
    __syncthreads();
    if (tid < 64) {
        float v = (tid < T) ? wsh[tid] : -INFINITY;
        float m = v;
        #pragma unroll
        for (int off = 32; off > 0; off >>= 1) m = fmaxf(m, __shfl_xor(m, off, 64));
        float e = (v == -INFINITY) ? 0.f : __expf(v - m);
        float ssum = e;
        #pragma unroll
        for (int off = 32; off > 0; off >>= 1) ssum += __shfl_xor(ssum, off, 64);
        const float inv = (ssum > 0.f) ? 1.f / ssum : 0.f;
        if (tid < T) wsh[tid] = e * inv;
    }
    __syncthreads();

    float o0 = 0.f, o1 = 0.f;
    #pragma unroll
    for (int t = 0; t < T; ++t) {
        float w = wsh[t];
        o0 += w * hsh[t][tid];
        o1 += w * hsh[t][tid + 128];
    }
    g_doc[(size_t)n * 256 + tid] = o0;
    g_doc[(size_t)n * 256 + tid + 128] = o1;
}

// ============================================================
// K6: classifier. Unchanged.
// ============================================================
__global__ __launch_bounds__(128) void k_classifier(
    const float* __restrict__ W1, const float* __restrict__ b1,
    const float* __restrict__ W2, const float* __restrict__ b2,
    float* __restrict__ out)
{
    const int b = blockIdx.x;
    __shared__ float dsh[256];
    __shared__ float hsh[128];
    const int tid = threadIdx.x;
    if (tid < 64) *(float4*)&dsh[tid * 4] = *(const float4*)&g_doc[(size_t)b * 256 + tid * 4];
    __syncthreads();
    float acc = 0.f;
    const float* w1p = &W1[tid * 256];
    for (int k = 0; k < 256; k += 4) {
        float4 w4 = *(const float4*)(w1p + k);
        float4 d4 = *(const float4*)&dsh[k];
        acc += dot4(w4, d4);
    }
    hsh[tid] = fmaxf(acc + b1[tid], 0.f);
    __syncthreads();
    if (tid < 3) {
        float a = b2[tid];
        const float* w2p = &W2[tid * 128];
        for (int j = 0; j < 128; ++j) a += w2p[j] * hsh[j];
        out[b * 3 + tid] = a;
    }
}

// ============================================================
extern "C" void kernel_launch(void* const* d_in, const int* in_sizes, int n_in,
                              void* d_out, int out_size, void* d_ws, size_t ws_size,
                              hipStream_t stream) {
    const int*   ids      = (const int*)d_in[0];
    const float* emb      = (const float*)d_in[1];
    const float* wl_Wih_f = (const float*)d_in[2];
    const float* wl_Whh_f = (const float*)d_in[3];
    const float* wl_bih_f = (const float*)d_in[4];
    const float* wl_bhh_f = (const float*)d_in[5];
    const float* wl_Wih_b = (const float*)d_in[6];
    const float* wl_Whh_b = (const float*)d_in[7];
    const float* wl_bih_b = (const float*)d_in[8];
    const float* wl_bhh_b = (const float*)d_in[9];
    const float* sl_Wih_f = (const float*)d_in[10];
    const float* sl_Whh_f = (const float*)d_in[11];
    const float* sl_bih_f = (const float*)d_in[12];
    const float* sl_bhh_f = (const float*)d_in[13];
    const float* sl_Wih_b = (const float*)d_in[14];
    const float* sl_Whh_b = (const float*)d_in[15];
    const float* sl_bih_b = (const float*)d_in[16];
    const float* sl_bhh_b = (const float*)d_in[17];
    const float* wa_W1 = (const float*)d_in[18];
    const float* wa_b1 = (const float*)d_in[19];
    const float* wa_W2 = (const float*)d_in[20];
    const float* wa_b2 = (const float*)d_in[21];
    const float* sa_W1 = (const float*)d_in[22];
    const float* sa_b1 = (const float*)d_in[23];
    const float* sa_W2 = (const float*)d_in[24];
    const float* sa_b2 = (const float*)d_in[25];
    const float* cl_W1 = (const float*)d_in[26];
    const float* cl_b1 = (const float*)d_in[27];
    const float* cl_W2 = (const float*)d_in[28];
    const float* cl_b2 = (const float*)d_in[29];

    k_split_w1<<<32, 256, 0, stream>>>(wa_W1);

    k_emb_proj<<<EP_NB * 2, 512, 0, stream>>>(
        emb, wl_Wih_f, wl_bih_f, wl_bhh_f, wl_Wih_b, wl_bih_b, wl_bhh_b);

    k_word_lstm<<<(NW / 32) * 2, 512, 0, stream>>>(ids, wl_Whh_f, wl_Whh_b);

    k_word_attn<<<NW, 256, 0, stream>>>(ids, wa_b1, wa_W2, wa_b2);

    k_sl_gin<<<NW / NSEQ_G * 2, 256, 0, stream>>>(
        sl_Wih_f, sl_bih_f, sl_bhh_f, sl_Wih_b, sl_bih_b, sl_bhh_b);

    k_sent_lstm<<<(B / 16) * 2, 512, 0, stream>>>(sl_Whh_f, sl_Whh_b);

    k_attn_pool_doc<S><<<B, 128, 0, stream>>>(ids, sa_W1, sa_b1, sa_W2, sa_b2);

    k_classifier<<<B, 128, 0, stream>>>(cl_W1, cl_b1, cl_W2, cl_b2, (float*)d_out);
}